// Round 11
// baseline (292.630 us; speedup 1.0000x reference)
//
#include <hip/hip_runtime.h>
#include <hip/hip_bf16.h>
#include <math.h>

#define N_NODES 50000
#define N_EDGES 800000
#define DIM 96
#define HEADS 4
#define HEAD_DIM 24
#define SLOPE 0.2f
#define LN_EPS 1e-5f

#define GT 192        // 3 waves; 12 feat-groups (8 feats) x 16 node-groups (4 nodes)
#define TNODES 64     // nodes per tile
#define XPAD 100      // x/g tile row stride (400B: 16B-aligned)
#define NTILES ((N_NODES + TNODES - 1) / TNODES)   // 782

#define SCAN_BLK 512
#define SCAN_NB ((N_NODES + SCAN_BLK - 1) / SCAN_BLK)   // 98

#define NPB 32                                     // nodes per bucket (d>>5)
#define NBUCK ((N_NODES + NPB - 1) / NPB)          // 1563

__device__ __forceinline__ unsigned short f2bf(float f) {
    unsigned u = __float_as_uint(f);
    u += 0x7FFFu + ((u >> 16) & 1u);          // round-to-nearest-even
    return (unsigned short)(u >> 16);
}
__device__ __forceinline__ float bf2f(unsigned short v) {
    return __uint_as_float(((unsigned)v) << 16);
}
__device__ __forceinline__ unsigned pack2bf(float a, float b) {
    return (unsigned)f2bf(a) | ((unsigned)f2bf(b) << 16);
}

// ---------------------------------------------------------------------------
// Prep: zero counts + transpose PW (PWT[k][f] = PW[f][k]) in one dispatch.
// ---------------------------------------------------------------------------
__global__ void k_prep(const float* __restrict__ PW, float* __restrict__ pwt,
                       int* __restrict__ counts)
{
    const int i = blockIdx.x * 256 + threadIdx.x;
    if (i < N_NODES) counts[i] = 0;
    if (i < DIM * DIM) pwt[i] = PW[(i % DIM) * DIM + i / DIM];
}

// ---------------------------------------------------------------------------
// Kernel A: h = x @ W, 4-node x 8-feat register tile, float4 LDS reads.
// (R9 measured-good config; GT=192.)
// ---------------------------------------------------------------------------
__global__ __launch_bounds__(GT) void k_transform(
    const float* __restrict__ x, const float* __restrict__ W,
    const float* __restrict__ attS, const float* __restrict__ attD,
    unsigned short* __restrict__ hb, float* __restrict__ asrc,
    float* __restrict__ adst)
{
    __shared__ float Wl[DIM][DIM];        // [k][f] 36.9 KB
    __shared__ float xl[TNODES][XPAD];    // 25.6 KB (reused as h-tile)
    __shared__ float attl[2][DIM];
    const int tid = threadIdx.x;
    for (int i4 = tid; i4 < DIM * (DIM / 4); i4 += GT) {     // float4 staging
        const int k = i4 / 24, q = i4 % 24;
        *(float4*)&Wl[k][q * 4] = *(const float4*)&W[k * DIM + q * 4];
    }
    if (tid < DIM) { attl[0][tid] = attS[tid]; attl[1][tid] = attD[tid]; }
    const int tf = tid % 12, tn = tid / 12;   // 12 feat-groups x 16 node-groups
    const int f0 = tf * 8, n0 = tn * 4;

    for (int tile = blockIdx.x; tile < NTILES; tile += gridDim.x) {
        const int base = tile * TNODES;
        __syncthreads();   // Wl ready (iter 0); xl consumers done (iter>0)
        for (int i4 = tid; i4 < TNODES * 24; i4 += GT) {
            const int n = i4 / 24, q = i4 % 24, gn = base + n;
            *(float4*)&xl[n][q * 4] = (gn < N_NODES)
                ? *(const float4*)&x[(size_t)gn * DIM + q * 4]
                : make_float4(0.f, 0.f, 0.f, 0.f);
        }
        __syncthreads();
        float acc[4][8] = {};
        for (int k = 0; k < DIM; k += 4) {
            float4 xq[4], wa[4], wb[4];
            #pragma unroll
            for (int a = 0; a < 4; ++a) xq[a] = *(const float4*)&xl[n0 + a][k];
            #pragma unroll
            for (int j = 0; j < 4; ++j) {
                wa[j] = *(const float4*)&Wl[k + j][f0];
                wb[j] = *(const float4*)&Wl[k + j][f0 + 4];
            }
            #pragma unroll
            for (int a = 0; a < 4; ++a) {
                const float x0 = xq[a].x, x1 = xq[a].y, x2 = xq[a].z, x3 = xq[a].w;
                acc[a][0] += x0*wa[0].x + x1*wa[1].x + x2*wa[2].x + x3*wa[3].x;
                acc[a][1] += x0*wa[0].y + x1*wa[1].y + x2*wa[2].y + x3*wa[3].y;
                acc[a][2] += x0*wa[0].z + x1*wa[1].z + x2*wa[2].z + x3*wa[3].z;
                acc[a][3] += x0*wa[0].w + x1*wa[1].w + x2*wa[2].w + x3*wa[3].w;
                acc[a][4] += x0*wb[0].x + x1*wb[1].x + x2*wb[2].x + x3*wb[3].x;
                acc[a][5] += x0*wb[0].y + x1*wb[1].y + x2*wb[2].y + x3*wb[3].y;
                acc[a][6] += x0*wb[0].z + x1*wb[1].z + x2*wb[2].z + x3*wb[3].z;
                acc[a][7] += x0*wb[0].w + x1*wb[1].w + x2*wb[2].w + x3*wb[3].w;
            }
        }
        #pragma unroll
        for (int a = 0; a < 4; ++a) {
            const int gn = base + n0 + a;
            if (gn < N_NODES) {
                uint4 hv;
                hv.x = pack2bf(acc[a][0], acc[a][1]);
                hv.y = pack2bf(acc[a][2], acc[a][3]);
                hv.z = pack2bf(acc[a][4], acc[a][5]);
                hv.w = pack2bf(acc[a][6], acc[a][7]);
                *(uint4*)&hb[(size_t)gn * DIM + f0] = hv;   // 8 bf16 = 16B
            }
        }
        __syncthreads();   // all xl reads done -> reuse as f32 h-tile
        #pragma unroll
        for (int a = 0; a < 4; ++a) {
            *(float4*)&xl[n0 + a][f0]     = make_float4(acc[a][0], acc[a][1], acc[a][2], acc[a][3]);
            *(float4*)&xl[n0 + a][f0 + 4] = make_float4(acc[a][4], acc[a][5], acc[a][6], acc[a][7]);
        }
        __syncthreads();
        for (int i = tid; i < TNODES * HEADS; i += GT) {     // (node, head) dots
            const int l = i >> 2, hd = i & 3, gn = base + l;
            if (gn < N_NODES) {
                float s = 0.f, dd = 0.f;
                #pragma unroll
                for (int kk = 0; kk < HEAD_DIM; ++kk) {
                    const float hv = xl[l][hd * HEAD_DIM + kk];
                    s  += hv * attl[0][hd * HEAD_DIM + kk];
                    dd += hv * attl[1][hd * HEAD_DIM + kk];
                }
                asrc[gn * HEADS + hd] = s;
                adst[gn * HEADS + hd] = dd;
            }
        }
    }
}

// ---------------------------------------------------------------------------
// CSR build: histogram -> partial sums -> fused final scan (+bucket cursors)
// ---------------------------------------------------------------------------
__global__ void k_hist(const int* __restrict__ ei, int* __restrict__ counts)
{
    const int e = blockIdx.x * 256 + threadIdx.x;
    if (e >= N_EDGES) return;
    const int d = ei[N_EDGES + e];
    if ((unsigned)d < N_NODES) atomicAdd(&counts[d], 1);
}

__global__ __launch_bounds__(SCAN_BLK) void k_scan_partial(
    const int* __restrict__ counts, int* __restrict__ bsum)
{
    __shared__ int red[SCAN_BLK];
    const int t = threadIdx.x;
    const int i = blockIdx.x * SCAN_BLK + t;
    red[t] = (i < N_NODES) ? counts[i] : 0;
    __syncthreads();
    #pragma unroll
    for (int off = SCAN_BLK / 2; off > 0; off >>= 1) {
        if (t < off) red[t] += red[t + off];
        __syncthreads();
    }
    if (t == 0) bsum[blockIdx.x] = red[0];
}

__global__ __launch_bounds__(SCAN_BLK) void k_scan_final(
    const int* __restrict__ counts, const int* __restrict__ bsum,
    int* __restrict__ offsets, int* __restrict__ bcur)
{
    __shared__ int s[SCAN_BLK];
    __shared__ int bs[128];
    const int t = threadIdx.x;
    if (t < 128) bs[t] = (t < SCAN_NB) ? bsum[t] : 0;
    __syncthreads();
    #pragma unroll
    for (int off = 1; off < 128; off <<= 1) {       // inclusive scan of bsum
        int u = 0;
        if (t < 128 && t >= off) u = bs[t - off];
        __syncthreads();
        if (t < 128) bs[t] += u;
        __syncthreads();
    }
    const int i = blockIdx.x * SCAN_BLK + t;
    const int v = (i < N_NODES) ? counts[i] : 0;
    s[t] = v;
    __syncthreads();
    #pragma unroll
    for (int off = 1; off < SCAN_BLK; off <<= 1) {
        const int u = (t >= off) ? s[t - off] : 0;
        __syncthreads();
        s[t] += u;
        __syncthreads();
    }
    const int bpre = (blockIdx.x == 0) ? 0 : bs[blockIdx.x - 1];
    if (i < N_NODES) {
        const int ex = bpre + s[t] - v;
        offsets[i] = ex;
        if ((i & (NPB - 1)) == 0) bcur[i / NPB] = ex;   // bucket append cursor
    }
    if (blockIdx.x == SCAN_NB - 1 && t == SCAN_BLK - 1)
        offsets[N_NODES] = bs[SCAN_NB - 1];         // total valid edges
}

// ---------------------------------------------------------------------------
// Bucketed scatter, pass 1: append packed (s,d) into the dst-bucket's
// contiguous CSR region (arrival order). 1563 streaming append points.
// ---------------------------------------------------------------------------
__global__ void k_bucket(const int* __restrict__ ei, int* __restrict__ bcur,
                         unsigned long long* __restrict__ staged)
{
    const int e = blockIdx.x * 256 + threadIdx.x;
    if (e >= N_EDGES) return;
    int s = ei[e];
    const int d = ei[N_EDGES + e];
    if ((unsigned)d >= N_NODES) return;
    if ((unsigned)s >= N_NODES) s = d;             // match k_hist validity
    const int pos = atomicAdd(&bcur[d >> 5], 1);
    staged[pos] = (unsigned long long)(unsigned)s |
                  ((unsigned long long)(unsigned)d << 32);
}

// ---------------------------------------------------------------------------
// Bucketed scatter, pass 2: one block per bucket; rank via 32 LDS cursors;
// coalesced staged reads, L2-hot 2KB-region ssrc writes.
// ---------------------------------------------------------------------------
__global__ __launch_bounds__(256) void k_sortbucket(
    const int* __restrict__ offsets, const unsigned long long* __restrict__ staged,
    int* __restrict__ ssrc)
{
    __shared__ int lcur[NPB];
    const int b = blockIdx.x;
    const int first = b * NPB;
    const int t = threadIdx.x;
    const int lastn = (first + NPB < N_NODES) ? first + NPB : N_NODES;
    if (t < NPB && first + t < N_NODES) lcur[t] = offsets[first + t];
    __syncthreads();
    const int rs = offsets[first];
    const int re = offsets[lastn];
    for (int idx = rs + t; idx < re; idx += 256) {
        const unsigned long long pk = staged[idx];
        const int s = (int)(pk & 0xffffffffu);
        const int d = (int)(pk >> 32);
        const int pos = atomicAdd(&lcur[d - first], 1);
        ssrc[pos] = s;
    }
}

// ---------------------------------------------------------------------------
// Kernel C: gather-aggregate, 8-deep software pipeline (+4-deep drain).
// One wave per dst node; lane l<48 owns feature pair (2l, 2l+1).
// Weights computed inline (asrc gather is L2-resident).
// ---------------------------------------------------------------------------
__global__ __launch_bounds__(256) void k_aggregate(
    const int* __restrict__ offsets, const int* __restrict__ ssrc,
    const unsigned short* __restrict__ hb, const float* __restrict__ asrc,
    const float* __restrict__ adst, const float* __restrict__ gb,
    unsigned short* __restrict__ gbuf)
{
    const int wid  = (blockIdx.x * 256 + threadIdx.x) >> 6;
    const int lane = threadIdx.x & 63;
    if (wid >= N_NODES) return;
    const int d = wid;
    const int lp = (lane < 48) ? lane : 47;     // lanes 48-63 duplicate lane 47
    const int f0 = lp * 2;                      // features f0, f0+1 (same head)
    const int hd = f0 / HEAD_DIM;

    const int rs = offsets[d], re = offsets[d + 1];
    const int deg = re - rs;
    const int sv = (lane < deg) ? ssrc[rs + lane] : 0;   // coalesced preload
    const float adw = adst[d * HEADS + hd];              // node-constant

    float acc0, acc1, ds;
    {   // self-loop term (overlaps the sv load latency)
        const unsigned int hp = *(const unsigned int*)&hb[(size_t)d * DIM + f0];
        float l0 = asrc[d * HEADS + hd] + adw;
        l0 = (l0 > 0.f) ? l0 : SLOPE * l0;
        const float w = __expf(l0);
        acc0 = w * bf2f((unsigned short)(hp & 0xffffu));
        acc1 = w * bf2f((unsigned short)(hp >> 16));
        ds = w;
    }

#define SRCJ(j) (((j) < 64) ? __shfl(sv, (j)) : ssrc[rs + (j)])
#define ISSUE(hreg, areg, j) do { \
        const int s_ = SRCJ(j); \
        hreg = *(const unsigned int*)&hb[(size_t)s_ * DIM + f0]; \
        areg = asrc[s_ * HEADS + hd]; } while (0)
#define CONSUME(hreg, areg) do { \
        float l_ = (areg) + adw; l_ = (l_ > 0.f) ? l_ : SLOPE * l_; \
        const float w_ = __expf(l_); \
        acc0 += w_ * bf2f((unsigned short)((hreg) & 0xffffu)); \
        acc1 += w_ * bf2f((unsigned short)((hreg) >> 16)); \
        ds += w_; } while (0)

    int j = 0;
    if (deg >= 8) {                             // 8-deep main pipeline
        unsigned p0, p1, p2, p3, p4, p5, p6, p7;
        float    q0, q1, q2, q3, q4, q5, q6, q7;
        ISSUE(p0, q0, 0); ISSUE(p1, q1, 1); ISSUE(p2, q2, 2); ISSUE(p3, q3, 3);
        ISSUE(p4, q4, 4); ISSUE(p5, q5, 5); ISSUE(p6, q6, 6); ISSUE(p7, q7, 7);
        for (; j + 16 <= deg; j += 8) {
            CONSUME(p0, q0); ISSUE(p0, q0, j + 8);
            CONSUME(p1, q1); ISSUE(p1, q1, j + 9);
            CONSUME(p2, q2); ISSUE(p2, q2, j + 10);
            CONSUME(p3, q3); ISSUE(p3, q3, j + 11);
            CONSUME(p4, q4); ISSUE(p4, q4, j + 12);
            CONSUME(p5, q5); ISSUE(p5, q5, j + 13);
            CONSUME(p6, q6); ISSUE(p6, q6, j + 14);
            CONSUME(p7, q7); ISSUE(p7, q7, j + 15);
        }
        CONSUME(p0, q0); CONSUME(p1, q1); CONSUME(p2, q2); CONSUME(p3, q3);
        CONSUME(p4, q4); CONSUME(p5, q5); CONSUME(p6, q6); CONSUME(p7, q7);
        j += 8;
    }
    if (j + 4 <= deg) {                         // 4-deep drain
        unsigned pa, pb_, pc, pd;
        float    qa, qb, qc, qd;
        ISSUE(pa, qa, j); ISSUE(pb_, qb, j + 1); ISSUE(pc, qc, j + 2); ISSUE(pd, qd, j + 3);
        CONSUME(pa, qa); CONSUME(pb_, qb); CONSUME(pc, qc); CONSUME(pd, qd);
        j += 4;
    }
    for (; j < deg; ++j) {                      // <=3 scalar tail
        unsigned hh; float aa;
        ISSUE(hh, aa, j); CONSUME(hh, aa);
    }
#undef SRCJ
#undef ISSUE
#undef CONSUME

    if (lane < 48) {
        const float inv = 1.f / ds;             // ds > 0 (self-loop)
        const float o0 = acc0 * inv + gb[f0];
        const float o1 = acc1 * inv + gb[f0 + 1];
        *(unsigned*)&gbuf[(size_t)d * DIM + f0] = pack2bf(o0, o1);
    }
}

// ---------------------------------------------------------------------------
// Kernel D: proj = g @ PW^T via pre-transposed PWT (row-major [k][f]),
// g staged from bf16, 4-node x 8-feat register tile, + residual + LN.
// ---------------------------------------------------------------------------
__global__ __launch_bounds__(GT) void k_finalize(
    const float* __restrict__ x, const float* __restrict__ PWT,
    const float* __restrict__ pb, const float* __restrict__ lng,
    const float* __restrict__ lnb, const unsigned short* __restrict__ gbuf,
    float* __restrict__ out)
{
    __shared__ float Wl[DIM][DIM];        // PWT tile [k][f] 36.9 KB
    __shared__ float gl[TNODES][XPAD];    // 25.6 KB (g tile, reused as z tile)
    __shared__ float sred[TNODES][6], s2red[TNODES][6];
    __shared__ float mubuf[TNODES], ivbuf[TNODES];
    __shared__ float lngl[DIM], lnbl[DIM];
    const int tid = threadIdx.x;
    for (int i4 = tid; i4 < DIM * (DIM / 4); i4 += GT) {
        const int k = i4 / 24, q = i4 % 24;
        *(float4*)&Wl[k][q * 4] = *(const float4*)&PWT[k * DIM + q * 4];
    }
    if (tid < DIM) { lngl[tid] = lng[tid]; lnbl[tid] = lnb[tid]; }
    const int tf = tid % 12, tn = tid / 12;
    const int f0 = tf * 8, n0 = tn * 4;
    const float4 pba = *(const float4*)&pb[f0];
    const float4 pbb = *(const float4*)&pb[f0 + 4];

    for (int tile = blockIdx.x; tile < NTILES; tile += gridDim.x) {
        const int base = tile * TNODES;
        __syncthreads();
        for (int i8 = tid; i8 < TNODES * 12; i8 += GT) {   // 8 bf16 per iter
            const int n = i8 / 12, q = i8 % 12, gn = base + n;
            float4 lo = make_float4(0.f, 0.f, 0.f, 0.f), hi = lo;
            if (gn < N_NODES) {
                const uint4 gv = *(const uint4*)&gbuf[(size_t)gn * DIM + q * 8];
                lo = make_float4(bf2f((unsigned short)(gv.x & 0xffffu)),
                                 bf2f((unsigned short)(gv.x >> 16)),
                                 bf2f((unsigned short)(gv.y & 0xffffu)),
                                 bf2f((unsigned short)(gv.y >> 16)));
                hi = make_float4(bf2f((unsigned short)(gv.z & 0xffffu)),
                                 bf2f((unsigned short)(gv.z >> 16)),
                                 bf2f((unsigned short)(gv.w & 0xffffu)),
                                 bf2f((unsigned short)(gv.w >> 16)));
            }
            *(float4*)&gl[n][q * 8]     = lo;
            *(float4*)&gl[n][q * 8 + 4] = hi;
        }
        __syncthreads();
        float acc[4][8] = {};
        for (int k = 0; k < DIM; k += 4) {
            float4 gq[4], wa[4], wb[4];
            #pragma unroll
            for (int a = 0; a < 4; ++a) gq[a] = *(const float4*)&gl[n0 + a][k];
            #pragma unroll
            for (int j = 0; j < 4; ++j) {
                wa[j] = *(const float4*)&Wl[k + j][f0];
                wb[j] = *(const float4*)&Wl[k + j][f0 + 4];
            }
            #pragma unroll
            for (int a = 0; a < 4; ++a) {
                const float g0 = gq[a].x, g1 = gq[a].y, g2 = gq[a].z, g3 = gq[a].w;
                acc[a][0] += g0*wa[0].x + g1*wa[1].x + g2*wa[2].x + g3*wa[3].x;
                acc[a][1] += g0*wa[0].y + g1*wa[1].y + g2*wa[2].y + g3*wa[3].y;
                acc[a][2] += g0*wa[0].z + g1*wa[1].z + g2*wa[2].z + g3*wa[3].z;
                acc[a][3] += g0*wa[0].w + g1*wa[1].w + g2*wa[2].w + g3*wa[3].w;
                acc[a][4] += g0*wb[0].x + g1*wb[1].x + g2*wb[2].x + g3*wb[3].x;
                acc[a][5] += g0*wb[0].y + g1*wb[1].y + g2*wb[2].y + g3*wb[3].y;
                acc[a][6] += g0*wb[0].z + g1*wb[1].z + g2*wb[2].z + g3*wb[3].z;
                acc[a][7] += g0*wb[0].w + g1*wb[1].w + g2*wb[2].w + g3*wb[3].w;
            }
        }
        // z = x + pb + proj (registers)
        float4 za[4], zb[4];
        #pragma unroll
        for (int a = 0; a < 4; ++a) {
            const int gn = base + n0 + a;
            float4 xa = make_float4(0.f,0.f,0.f,0.f), xb = xa;
            if (gn < N_NODES) {
                xa = *(const float4*)&x[(size_t)gn * DIM + f0];
                xb = *(const float4*)&x[(size_t)gn * DIM + f0 + 4];
            }
            za[a] = make_float4(acc[a][0]+pba.x+xa.x, acc[a][1]+pba.y+xa.y,
                                acc[a][2]+pba.z+xa.z, acc[a][3]+pba.w+xa.w);
            zb[a] = make_float4(acc[a][4]+pbb.x+xb.x, acc[a][5]+pbb.y+xb.y,
                                acc[a][6]+pbb.z+xb.z, acc[a][7]+pbb.w+xb.w);
        }
        __syncthreads();   // gl (g) reads done -> reuse as z tile
        #pragma unroll
        for (int a = 0; a < 4; ++a) {
            *(float4*)&gl[n0 + a][f0]     = za[a];
            *(float4*)&gl[n0 + a][f0 + 4] = zb[a];
        }
        __syncthreads();
        for (int i = tid; i < TNODES * 6; i += GT) {   // partials: 6/node x 16
            const int n = i / 6, jj = i % 6;
            float s = 0.f, s2 = 0.f;
            #pragma unroll
            for (int c = 0; c < 16; ++c) {
                const float v = gl[n][jj * 16 + c];
                s += v; s2 += v * v;
            }
            sred[n][jj] = s; s2red[n][jj] = s2;
        }
        __syncthreads();
        if (tid < TNODES) {
            float s = 0.f, s2 = 0.f;
            #pragma unroll
            for (int jj = 0; jj < 6; ++jj) { s += sred[tid][jj]; s2 += s2red[tid][jj]; }
            const float mu = s * (1.f / DIM);
            const float var = s2 * (1.f / DIM) - mu * mu;
            mubuf[tid] = mu;
            ivbuf[tid] = rsqrtf(var + LN_EPS);
        }
        __syncthreads();
        for (int i = tid; i < TNODES * 24; i += GT) {
            const int n = i / 24, c = i % 24, gn = base + n;
            if (gn < N_NODES) {
                const float4 v = *(const float4*)&gl[n][c * 4];
                const float mu = mubuf[n], iv = ivbuf[n];
                float4 o;
                o.x = lngl[c*4+0] * (v.x - mu) * iv + lnbl[c*4+0];
                o.y = lngl[c*4+1] * (v.y - mu) * iv + lnbl[c*4+1];
                o.z = lngl[c*4+2] * (v.z - mu) * iv + lnbl[c*4+2];
                o.w = lngl[c*4+3] * (v.w - mu) * iv + lnbl[c*4+3];
                *(float4*)&out[(size_t)gn * DIM + c * 4] = o;
            }
        }
    }
}

// ---------------------------------------------------------------------------
extern "C" void kernel_launch(void* const* d_in, const int* in_sizes, int n_in,
                              void* d_out, int out_size, void* d_ws, size_t ws_size,
                              hipStream_t stream)
{
    const float* x    = (const float*)d_in[0];
    const int*   ei   = (const int*)d_in[1];     // [2, E] int32 (harness-converted)
    const float* W    = (const float*)d_in[2];
    const float* attS = (const float*)d_in[3];
    const float* attD = (const float*)d_in[4];
    const float* gb   = (const float*)d_in[5];
    const float* PW   = (const float*)d_in[6];
    const float* pb   = (const float*)d_in[7];
    const float* lng  = (const float*)d_in[8];
    const float* lnb  = (const float*)d_in[9];
    float* out = (float*)d_out;

    char* ws = (char*)d_ws;
    unsigned long long* staged = (unsigned long long*)ws;         // E*8 (6.4 MB)
    float* asrc    = (float*)(staged + N_EDGES);                  // N*4
    float* adst    = asrc + N_NODES * HEADS;                      // N*4
    unsigned short* hb   = (unsigned short*)(adst + N_NODES * HEADS); // N*96 bf16
    unsigned short* gbuf = hb + (size_t)N_NODES * DIM;            // N*96 bf16
    float* pwt     = (float*)(gbuf + (size_t)N_NODES * DIM);      // 96*96 f32
    int*   counts  = (int*)(pwt + DIM * DIM);                     // N
    int*   offsets = counts + N_NODES;                            // N+1
    int*   bsum    = offsets + N_NODES + 1;                       // SCAN_NB
    int*   bcur    = bsum + SCAN_NB;                              // NBUCK
    int*   ssrc    = bcur + NBUCK;                                // E

    k_prep        <<<(N_NODES + 255) / 256, 256, 0, stream>>>(PW, pwt, counts);
    k_hist        <<<(N_EDGES + 255) / 256, 256, 0, stream>>>(ei, counts);
    k_scan_partial<<<SCAN_NB, SCAN_BLK, 0, stream>>>(counts, bsum);
    k_scan_final  <<<SCAN_NB, SCAN_BLK, 0, stream>>>(counts, bsum, offsets, bcur);
    k_bucket      <<<(N_EDGES + 255) / 256, 256, 0, stream>>>(ei, bcur, staged);
    k_sortbucket  <<<NBUCK, 256, 0, stream>>>(offsets, staged, ssrc);
    k_transform   <<<NTILES, GT, 0, stream>>>(x, W, attS, attD, hb, asrc, adst);
    k_aggregate   <<<(N_NODES * 64 + 255) / 256, 256, 0, stream>>>(offsets, ssrc, hb, asrc, adst, gb, gbuf);
    k_finalize    <<<NTILES, GT, 0, stream>>>(x, pwt, pb, lng, lnb, gbuf, out);
}

// Round 12
// 152.730 us; speedup vs baseline: 1.9160x; 1.9160x over previous
//
#include <hip/hip_runtime.h>
#include <hip/hip_bf16.h>
#include <math.h>

#define N_NODES 50000
#define N_EDGES 800000
#define DIM 96
#define HEADS 4
#define HEAD_DIM 24
#define SLOPE 0.2f
#define LN_EPS 1e-5f

#define GT 192        // 3 waves; 12 feat-groups (8 feats) x 16 node-groups (4 nodes)
#define TNODES 64     // nodes per tile
#define XPAD 100      // x/g tile row stride (400B: 16B-aligned)
#define NTILES ((N_NODES + TNODES - 1) / TNODES)   // 782

#define CH 2048                                    // edges per sort chunk
#define NCH ((N_EDGES + CH - 1) / CH)              // 391
#define NB2 ((N_NODES + 255) / 256)                // 196 coarse buckets (dst>>8)

__device__ __forceinline__ unsigned short f2bf(float f) {
    unsigned u = __float_as_uint(f);
    u += 0x7FFFu + ((u >> 16) & 1u);          // round-to-nearest-even
    return (unsigned short)(u >> 16);
}
__device__ __forceinline__ float bf2f(unsigned short v) {
    return __uint_as_float(((unsigned)v) << 16);
}
__device__ __forceinline__ unsigned pack2bf(float a, float b) {
    return (unsigned)f2bf(a) | ((unsigned)f2bf(b) << 16);
}

// ---------------------------------------------------------------------------
// Prep: transpose PW (PWT[k][f] = PW[f][k]).
// ---------------------------------------------------------------------------
__global__ void k_prep(const float* __restrict__ PW, float* __restrict__ pwt)
{
    const int i = blockIdx.x * 256 + threadIdx.x;
    if (i < DIM * DIM) pwt[i] = PW[(i % DIM) * DIM + i / DIM];
}

// ---------------------------------------------------------------------------
// Sort pass A: per-chunk LDS histogram over 196 coarse buckets -> cnt[k][b].
// No global atomics.
// ---------------------------------------------------------------------------
__global__ __launch_bounds__(256) void k_sortA(const int* __restrict__ ei,
                                               int* __restrict__ cnt)
{
    __shared__ int h[NB2];
    const int b = blockIdx.x, t = threadIdx.x;
    for (int k = t; k < NB2; k += 256) h[k] = 0;
    __syncthreads();
    const int e0 = b * CH;
    const int e1 = (e0 + CH < N_EDGES) ? e0 + CH : N_EDGES;
    for (int e = e0 + t; e < e1; e += 256) {
        const int d = ei[N_EDGES + e];
        if ((unsigned)d < N_NODES) atomicAdd(&h[d >> 8], 1);
    }
    __syncthreads();
    for (int k = t; k < NB2; k += 256) cnt[k * NCH + b] = h[k];
}

// ---------------------------------------------------------------------------
// Sort pass B1: per-bucket scan over chunks (contiguous row) -> colpre, colsum.
// ---------------------------------------------------------------------------
__global__ __launch_bounds__(512) void k_sortB1(const int* __restrict__ cnt,
                                                int* __restrict__ colpre,
                                                int* __restrict__ colsum)
{
    __shared__ int s[512];
    const int k = blockIdx.x, t = threadIdx.x;
    const int v = (t < NCH) ? cnt[k * NCH + t] : 0;
    s[t] = v;
    __syncthreads();
    #pragma unroll
    for (int off = 1; off < 512; off <<= 1) {
        const int u = (t >= off) ? s[t - off] : 0;
        __syncthreads();
        s[t] += u;
        __syncthreads();
    }
    if (t < NCH) colpre[k * NCH + t] = s[t] - v;
    if (t == 511) colsum[k] = s[511];
}

// ---------------------------------------------------------------------------
// Sort pass B2: scan 196 bucket totals -> bbase[0..NB2] (exclusive + total).
// ---------------------------------------------------------------------------
__global__ __launch_bounds__(256) void k_sortB2(const int* __restrict__ colsum,
                                                int* __restrict__ bbase)
{
    __shared__ int s[256];
    const int t = threadIdx.x;
    const int v = (t < NB2) ? colsum[t] : 0;
    s[t] = v;
    __syncthreads();
    #pragma unroll
    for (int off = 1; off < 256; off <<= 1) {
        const int u = (t >= off) ? s[t - off] : 0;
        __syncthreads();
        s[t] += u;
        __syncthreads();
    }
    if (t < NB2) bbase[t] = s[t] - v;
    if (t == 255) bbase[NB2] = s[255];
}

// ---------------------------------------------------------------------------
// Sort pass C: place packed (s,d) into coarse-bucket order. LDS cursors only;
// each (chunk,bucket) run is a contiguous ~80B write.
// ---------------------------------------------------------------------------
__global__ __launch_bounds__(256) void k_sortC(const int* __restrict__ ei,
                                               const int* __restrict__ colpre,
                                               const int* __restrict__ bbase,
                                               unsigned long long* __restrict__ staged)
{
    __shared__ int lcur[NB2];
    const int b = blockIdx.x, t = threadIdx.x;
    for (int k = t; k < NB2; k += 256) lcur[k] = bbase[k] + colpre[k * NCH + b];
    __syncthreads();
    const int e0 = b * CH;
    const int e1 = (e0 + CH < N_EDGES) ? e0 + CH : N_EDGES;
    for (int e = e0 + t; e < e1; e += 256) {
        int s = ei[e];
        const int d = ei[N_EDGES + e];
        if ((unsigned)d >= N_NODES) continue;
        if ((unsigned)s >= N_NODES) s = d;
        const int pos = atomicAdd(&lcur[d >> 8], 1);
        staged[pos] = (unsigned long long)(unsigned)s |
                      ((unsigned long long)(unsigned)d << 32);
    }
}

// ---------------------------------------------------------------------------
// Sort pass D: one block per coarse bucket (256 nodes). Node histogram + LDS
// scan -> writes offsets slice (coalesced) and final dst-sorted ssrc (writes
// land in a ~16KB L2-hot region). LDS atomics only.
// ---------------------------------------------------------------------------
__global__ __launch_bounds__(512) void k_sortD(
    const unsigned long long* __restrict__ staged, const int* __restrict__ bbase,
    int* __restrict__ offsets, int* __restrict__ ssrc)
{
    __shared__ int hist[256];
    __shared__ int sc[256];
    const int k = blockIdx.x, t = threadIdx.x;
    const int first = k << 8;
    const int nn = (first + 256 < N_NODES) ? 256 : N_NODES - first;
    const int rs = bbase[k], re = bbase[k + 1];
    if (t < 256) hist[t] = 0;
    __syncthreads();
    for (int i = rs + t; i < re; i += 512) {
        const int d = (int)(staged[i] >> 32);
        atomicAdd(&hist[d - first], 1);
    }
    __syncthreads();
    if (t < 256) sc[t] = hist[t];
    __syncthreads();
    #pragma unroll
    for (int off = 1; off < 256; off <<= 1) {
        int u = 0;
        if (t < 256 && t >= off) u = sc[t - off];
        __syncthreads();
        if (t < 256) sc[t] += u;
        __syncthreads();
    }
    int mycur = 0;
    if (t < 256) {
        mycur = rs + sc[t] - hist[t];           // exclusive position
        if (t < nn) offsets[first + t] = mycur;
    }
    if (k == 0 && t == 0) offsets[N_NODES] = bbase[NB2];
    __syncthreads();
    if (t < 256) hist[t] = mycur;               // reuse hist as cursor
    __syncthreads();
    for (int i = rs + t; i < re; i += 512) {
        const unsigned long long pk = staged[i];
        const int s = (int)(pk & 0xffffffffu);
        const int d = (int)(pk >> 32);
        const int pos = atomicAdd(&hist[d - first], 1);
        ssrc[pos] = s;
    }
}

// ---------------------------------------------------------------------------
// Kernel A: h = x @ W, 4-node x 8-feat register tile, float4 LDS reads.
// ---------------------------------------------------------------------------
__global__ __launch_bounds__(GT) void k_transform(
    const float* __restrict__ x, const float* __restrict__ W,
    const float* __restrict__ attS, const float* __restrict__ attD,
    unsigned short* __restrict__ hb, float* __restrict__ asrc,
    float* __restrict__ adst)
{
    __shared__ float Wl[DIM][DIM];        // [k][f] 36.9 KB
    __shared__ float xl[TNODES][XPAD];    // 25.6 KB (reused as h-tile)
    __shared__ float attl[2][DIM];
    const int tid = threadIdx.x;
    for (int i4 = tid; i4 < DIM * (DIM / 4); i4 += GT) {     // float4 staging
        const int k = i4 / 24, q = i4 % 24;
        *(float4*)&Wl[k][q * 4] = *(const float4*)&W[k * DIM + q * 4];
    }
    if (tid < DIM) { attl[0][tid] = attS[tid]; attl[1][tid] = attD[tid]; }
    const int tf = tid % 12, tn = tid / 12;   // 12 feat-groups x 16 node-groups
    const int f0 = tf * 8, n0 = tn * 4;

    for (int tile = blockIdx.x; tile < NTILES; tile += gridDim.x) {
        const int base = tile * TNODES;
        __syncthreads();   // Wl ready (iter 0); xl consumers done (iter>0)
        for (int i4 = tid; i4 < TNODES * 24; i4 += GT) {
            const int n = i4 / 24, q = i4 % 24, gn = base + n;
            *(float4*)&xl[n][q * 4] = (gn < N_NODES)
                ? *(const float4*)&x[(size_t)gn * DIM + q * 4]
                : make_float4(0.f, 0.f, 0.f, 0.f);
        }
        __syncthreads();
        float acc[4][8] = {};
        for (int k = 0; k < DIM; k += 4) {
            float4 xq[4], wa[4], wb[4];
            #pragma unroll
            for (int a = 0; a < 4; ++a) xq[a] = *(const float4*)&xl[n0 + a][k];
            #pragma unroll
            for (int j = 0; j < 4; ++j) {
                wa[j] = *(const float4*)&Wl[k + j][f0];
                wb[j] = *(const float4*)&Wl[k + j][f0 + 4];
            }
            #pragma unroll
            for (int a = 0; a < 4; ++a) {
                const float x0 = xq[a].x, x1 = xq[a].y, x2 = xq[a].z, x3 = xq[a].w;
                acc[a][0] += x0*wa[0].x + x1*wa[1].x + x2*wa[2].x + x3*wa[3].x;
                acc[a][1] += x0*wa[0].y + x1*wa[1].y + x2*wa[2].y + x3*wa[3].y;
                acc[a][2] += x0*wa[0].z + x1*wa[1].z + x2*wa[2].z + x3*wa[3].z;
                acc[a][3] += x0*wa[0].w + x1*wa[1].w + x2*wa[2].w + x3*wa[3].w;
                acc[a][4] += x0*wb[0].x + x1*wb[1].x + x2*wb[2].x + x3*wb[3].x;
                acc[a][5] += x0*wb[0].y + x1*wb[1].y + x2*wb[2].y + x3*wb[3].y;
                acc[a][6] += x0*wb[0].z + x1*wb[1].z + x2*wb[2].z + x3*wb[3].z;
                acc[a][7] += x0*wb[0].w + x1*wb[1].w + x2*wb[2].w + x3*wb[3].w;
            }
        }
        #pragma unroll
        for (int a = 0; a < 4; ++a) {
            const int gn = base + n0 + a;
            if (gn < N_NODES) {
                uint4 hv;
                hv.x = pack2bf(acc[a][0], acc[a][1]);
                hv.y = pack2bf(acc[a][2], acc[a][3]);
                hv.z = pack2bf(acc[a][4], acc[a][5]);
                hv.w = pack2bf(acc[a][6], acc[a][7]);
                *(uint4*)&hb[(size_t)gn * DIM + f0] = hv;   // 8 bf16 = 16B
            }
        }
        __syncthreads();   // all xl reads done -> reuse as f32 h-tile
        #pragma unroll
        for (int a = 0; a < 4; ++a) {
            *(float4*)&xl[n0 + a][f0]     = make_float4(acc[a][0], acc[a][1], acc[a][2], acc[a][3]);
            *(float4*)&xl[n0 + a][f0 + 4] = make_float4(acc[a][4], acc[a][5], acc[a][6], acc[a][7]);
        }
        __syncthreads();
        for (int i = tid; i < TNODES * HEADS; i += GT) {     // (node, head) dots
            const int l = i >> 2, hd = i & 3, gn = base + l;
            if (gn < N_NODES) {
                float s = 0.f, dd = 0.f;
                #pragma unroll
                for (int kk = 0; kk < HEAD_DIM; ++kk) {
                    const float hv = xl[l][hd * HEAD_DIM + kk];
                    s  += hv * attl[0][hd * HEAD_DIM + kk];
                    dd += hv * attl[1][hd * HEAD_DIM + kk];
                }
                asrc[gn * HEADS + hd] = s;
                adst[gn * HEADS + hd] = dd;
            }
        }
    }
}

// ---------------------------------------------------------------------------
// Kernel C: gather-aggregate, 8-deep software pipeline (+4-deep drain).
// One wave per dst node; lane l<48 owns feature pair (2l, 2l+1).
// Weights computed inline (asrc gather is L2-resident).
// ---------------------------------------------------------------------------
__global__ __launch_bounds__(256) void k_aggregate(
    const int* __restrict__ offsets, const int* __restrict__ ssrc,
    const unsigned short* __restrict__ hb, const float* __restrict__ asrc,
    const float* __restrict__ adst, const float* __restrict__ gb,
    unsigned short* __restrict__ gbuf)
{
    const int wid  = (blockIdx.x * 256 + threadIdx.x) >> 6;
    const int lane = threadIdx.x & 63;
    if (wid >= N_NODES) return;
    const int d = wid;
    const int lp = (lane < 48) ? lane : 47;     // lanes 48-63 duplicate lane 47
    const int f0 = lp * 2;                      // features f0, f0+1 (same head)
    const int hd = f0 / HEAD_DIM;

    const int rs = offsets[d], re = offsets[d + 1];
    const int deg = re - rs;
    const int sv = (lane < deg) ? ssrc[rs + lane] : 0;   // coalesced preload
    const float adw = adst[d * HEADS + hd];              // node-constant

    float acc0, acc1, ds;
    {   // self-loop term (overlaps the sv load latency)
        const unsigned int hp = *(const unsigned int*)&hb[(size_t)d * DIM + f0];
        float l0 = asrc[d * HEADS + hd] + adw;
        l0 = (l0 > 0.f) ? l0 : SLOPE * l0;
        const float w = __expf(l0);
        acc0 = w * bf2f((unsigned short)(hp & 0xffffu));
        acc1 = w * bf2f((unsigned short)(hp >> 16));
        ds = w;
    }

#define SRCJ(j) (((j) < 64) ? __shfl(sv, (j)) : ssrc[rs + (j)])
#define ISSUE(hreg, areg, j) do { \
        const int s_ = SRCJ(j); \
        hreg = *(const unsigned int*)&hb[(size_t)s_ * DIM + f0]; \
        areg = asrc[s_ * HEADS + hd]; } while (0)
#define CONSUME(hreg, areg) do { \
        float l_ = (areg) + adw; l_ = (l_ > 0.f) ? l_ : SLOPE * l_; \
        const float w_ = __expf(l_); \
        acc0 += w_ * bf2f((unsigned short)((hreg) & 0xffffu)); \
        acc1 += w_ * bf2f((unsigned short)((hreg) >> 16)); \
        ds += w_; } while (0)

    int j = 0;
    if (deg >= 8) {                             // 8-deep main pipeline
        unsigned p0, p1, p2, p3, p4, p5, p6, p7;
        float    q0, q1, q2, q3, q4, q5, q6, q7;
        ISSUE(p0, q0, 0); ISSUE(p1, q1, 1); ISSUE(p2, q2, 2); ISSUE(p3, q3, 3);
        ISSUE(p4, q4, 4); ISSUE(p5, q5, 5); ISSUE(p6, q6, 6); ISSUE(p7, q7, 7);
        for (; j + 16 <= deg; j += 8) {
            CONSUME(p0, q0); ISSUE(p0, q0, j + 8);
            CONSUME(p1, q1); ISSUE(p1, q1, j + 9);
            CONSUME(p2, q2); ISSUE(p2, q2, j + 10);
            CONSUME(p3, q3); ISSUE(p3, q3, j + 11);
            CONSUME(p4, q4); ISSUE(p4, q4, j + 12);
            CONSUME(p5, q5); ISSUE(p5, q5, j + 13);
            CONSUME(p6, q6); ISSUE(p6, q6, j + 14);
            CONSUME(p7, q7); ISSUE(p7, q7, j + 15);
        }
        CONSUME(p0, q0); CONSUME(p1, q1); CONSUME(p2, q2); CONSUME(p3, q3);
        CONSUME(p4, q4); CONSUME(p5, q5); CONSUME(p6, q6); CONSUME(p7, q7);
        j += 8;
    }
    if (j + 4 <= deg) {                         // 4-deep drain
        unsigned pa, pb_, pc, pd;
        float    qa, qb, qc, qd;
        ISSUE(pa, qa, j); ISSUE(pb_, qb, j + 1); ISSUE(pc, qc, j + 2); ISSUE(pd, qd, j + 3);
        CONSUME(pa, qa); CONSUME(pb_, qb); CONSUME(pc, qc); CONSUME(pd, qd);
        j += 4;
    }
    for (; j < deg; ++j) {                      // <=3 scalar tail
        unsigned hh; float aa;
        ISSUE(hh, aa, j); CONSUME(hh, aa);
    }
#undef SRCJ
#undef ISSUE
#undef CONSUME

    if (lane < 48) {
        const float inv = 1.f / ds;             // ds > 0 (self-loop)
        const float o0 = acc0 * inv + gb[f0];
        const float o1 = acc1 * inv + gb[f0 + 1];
        *(unsigned*)&gbuf[(size_t)d * DIM + f0] = pack2bf(o0, o1);
    }
}

// ---------------------------------------------------------------------------
// Kernel D: proj = g @ PW^T via pre-transposed PWT (row-major [k][f]),
// g staged from bf16, 4-node x 8-feat register tile, + residual + LN.
// ---------------------------------------------------------------------------
__global__ __launch_bounds__(GT) void k_finalize(
    const float* __restrict__ x, const float* __restrict__ PWT,
    const float* __restrict__ pb, const float* __restrict__ lng,
    const float* __restrict__ lnb, const unsigned short* __restrict__ gbuf,
    float* __restrict__ out)
{
    __shared__ float Wl[DIM][DIM];        // PWT tile [k][f] 36.9 KB
    __shared__ float gl[TNODES][XPAD];    // 25.6 KB (g tile, reused as z tile)
    __shared__ float sred[TNODES][6], s2red[TNODES][6];
    __shared__ float mubuf[TNODES], ivbuf[TNODES];
    __shared__ float lngl[DIM], lnbl[DIM];
    const int tid = threadIdx.x;
    for (int i4 = tid; i4 < DIM * (DIM / 4); i4 += GT) {
        const int k = i4 / 24, q = i4 % 24;
        *(float4*)&Wl[k][q * 4] = *(const float4*)&PWT[k * DIM + q * 4];
    }
    if (tid < DIM) { lngl[tid] = lng[tid]; lnbl[tid] = lnb[tid]; }
    const int tf = tid % 12, tn = tid / 12;
    const int f0 = tf * 8, n0 = tn * 4;
    const float4 pba = *(const float4*)&pb[f0];
    const float4 pbb = *(const float4*)&pb[f0 + 4];

    for (int tile = blockIdx.x; tile < NTILES; tile += gridDim.x) {
        const int base = tile * TNODES;
        __syncthreads();
        for (int i8 = tid; i8 < TNODES * 12; i8 += GT) {   // 8 bf16 per iter
            const int n = i8 / 12, q = i8 % 12, gn = base + n;
            float4 lo = make_float4(0.f, 0.f, 0.f, 0.f), hi = lo;
            if (gn < N_NODES) {
                const uint4 gv = *(const uint4*)&gbuf[(size_t)gn * DIM + q * 8];
                lo = make_float4(bf2f((unsigned short)(gv.x & 0xffffu)),
                                 bf2f((unsigned short)(gv.x >> 16)),
                                 bf2f((unsigned short)(gv.y & 0xffffu)),
                                 bf2f((unsigned short)(gv.y >> 16)));
                hi = make_float4(bf2f((unsigned short)(gv.z & 0xffffu)),
                                 bf2f((unsigned short)(gv.z >> 16)),
                                 bf2f((unsigned short)(gv.w & 0xffffu)),
                                 bf2f((unsigned short)(gv.w >> 16)));
            }
            *(float4*)&gl[n][q * 8]     = lo;
            *(float4*)&gl[n][q * 8 + 4] = hi;
        }
        __syncthreads();
        float acc[4][8] = {};
        for (int k = 0; k < DIM; k += 4) {
            float4 gq[4], wa[4], wb[4];
            #pragma unroll
            for (int a = 0; a < 4; ++a) gq[a] = *(const float4*)&gl[n0 + a][k];
            #pragma unroll
            for (int j = 0; j < 4; ++j) {
                wa[j] = *(const float4*)&Wl[k + j][f0];
                wb[j] = *(const float4*)&Wl[k + j][f0 + 4];
            }
            #pragma unroll
            for (int a = 0; a < 4; ++a) {
                const float g0 = gq[a].x, g1 = gq[a].y, g2 = gq[a].z, g3 = gq[a].w;
                acc[a][0] += g0*wa[0].x + g1*wa[1].x + g2*wa[2].x + g3*wa[3].x;
                acc[a][1] += g0*wa[0].y + g1*wa[1].y + g2*wa[2].y + g3*wa[3].y;
                acc[a][2] += g0*wa[0].z + g1*wa[1].z + g2*wa[2].z + g3*wa[3].z;
                acc[a][3] += g0*wa[0].w + g1*wa[1].w + g2*wa[2].w + g3*wa[3].w;
                acc[a][4] += g0*wb[0].x + g1*wb[1].x + g2*wb[2].x + g3*wb[3].x;
                acc[a][5] += g0*wb[0].y + g1*wb[1].y + g2*wb[2].y + g3*wb[3].y;
                acc[a][6] += g0*wb[0].z + g1*wb[1].z + g2*wb[2].z + g3*wb[3].z;
                acc[a][7] += g0*wb[0].w + g1*wb[1].w + g2*wb[2].w + g3*wb[3].w;
            }
        }
        // z = x + pb + proj (registers)
        float4 za[4], zb[4];
        #pragma unroll
        for (int a = 0; a < 4; ++a) {
            const int gn = base + n0 + a;
            float4 xa = make_float4(0.f,0.f,0.f,0.f), xb = xa;
            if (gn < N_NODES) {
                xa = *(const float4*)&x[(size_t)gn * DIM + f0];
                xb = *(const float4*)&x[(size_t)gn * DIM + f0 + 4];
            }
            za[a] = make_float4(acc[a][0]+pba.x+xa.x, acc[a][1]+pba.y+xa.y,
                                acc[a][2]+pba.z+xa.z, acc[a][3]+pba.w+xa.w);
            zb[a] = make_float4(acc[a][4]+pbb.x+xb.x, acc[a][5]+pbb.y+xb.y,
                                acc[a][6]+pbb.z+xb.z, acc[a][7]+pbb.w+xb.w);
        }
        __syncthreads();   // gl (g) reads done -> reuse as z tile
        #pragma unroll
        for (int a = 0; a < 4; ++a) {
            *(float4*)&gl[n0 + a][f0]     = za[a];
            *(float4*)&gl[n0 + a][f0 + 4] = zb[a];
        }
        __syncthreads();
        for (int i = tid; i < TNODES * 6; i += GT) {   // partials: 6/node x 16
            const int n = i / 6, jj = i % 6;
            float s = 0.f, s2 = 0.f;
            #pragma unroll
            for (int c = 0; c < 16; ++c) {
                const float v = gl[n][jj * 16 + c];
                s += v; s2 += v * v;
            }
            sred[n][jj] = s; s2red[n][jj] = s2;
        }
        __syncthreads();
        if (tid < TNODES) {
            float s = 0.f, s2 = 0.f;
            #pragma unroll
            for (int jj = 0; jj < 6; ++jj) { s += sred[tid][jj]; s2 += s2red[tid][jj]; }
            const float mu = s * (1.f / DIM);
            const float var = s2 * (1.f / DIM) - mu * mu;
            mubuf[tid] = mu;
            ivbuf[tid] = rsqrtf(var + LN_EPS);
        }
        __syncthreads();
        for (int i = tid; i < TNODES * 24; i += GT) {
            const int n = i / 24, c = i % 24, gn = base + n;
            if (gn < N_NODES) {
                const float4 v = *(const float4*)&gl[n][c * 4];
                const float mu = mubuf[n], iv = ivbuf[n];
                float4 o;
                o.x = lngl[c*4+0] * (v.x - mu) * iv + lnbl[c*4+0];
                o.y = lngl[c*4+1] * (v.y - mu) * iv + lnbl[c*4+1];
                o.z = lngl[c*4+2] * (v.z - mu) * iv + lnbl[c*4+2];
                o.w = lngl[c*4+3] * (v.w - mu) * iv + lnbl[c*4+3];
                *(float4*)&out[(size_t)gn * DIM + c * 4] = o;
            }
        }
    }
}

// ---------------------------------------------------------------------------
extern "C" void kernel_launch(void* const* d_in, const int* in_sizes, int n_in,
                              void* d_out, int out_size, void* d_ws, size_t ws_size,
                              hipStream_t stream)
{
    const float* x    = (const float*)d_in[0];
    const int*   ei   = (const int*)d_in[1];     // [2, E] int32 (harness-converted)
    const float* W    = (const float*)d_in[2];
    const float* attS = (const float*)d_in[3];
    const float* attD = (const float*)d_in[4];
    const float* gb   = (const float*)d_in[5];
    const float* PW   = (const float*)d_in[6];
    const float* pb   = (const float*)d_in[7];
    const float* lng  = (const float*)d_in[8];
    const float* lnb  = (const float*)d_in[9];
    float* out = (float*)d_out;

    char* ws = (char*)d_ws;
    unsigned long long* staged = (unsigned long long*)ws;         // E*8 (6.4 MB)
    float* asrc    = (float*)(staged + N_EDGES);                  // N*4
    float* adst    = asrc + N_NODES * HEADS;                      // N*4
    unsigned short* hb   = (unsigned short*)(adst + N_NODES * HEADS); // N*96 bf16
    unsigned short* gbuf = hb + (size_t)N_NODES * DIM;            // N*96 bf16
    float* pwt     = (float*)(gbuf + (size_t)N_NODES * DIM);      // 96*96 f32
    int*   cnt     = (int*)(pwt + DIM * DIM);                     // NB2*NCH
    int*   colpre  = cnt + NB2 * NCH;                             // NB2*NCH
    int*   colsum  = colpre + NB2 * NCH;                          // NB2
    int*   bbase   = colsum + NB2;                                // NB2+1
    int*   offsets = bbase + NB2 + 1;                             // N+1
    int*   ssrc    = offsets + N_NODES + 1;                       // E

    k_prep     <<<(DIM * DIM + 255) / 256, 256, 0, stream>>>(PW, pwt);
    k_sortA    <<<NCH, 256, 0, stream>>>(ei, cnt);
    k_sortB1   <<<NB2, 512, 0, stream>>>(cnt, colpre, colsum);
    k_sortB2   <<<1, 256, 0, stream>>>(colsum, bbase);
    k_sortC    <<<NCH, 256, 0, stream>>>(ei, colpre, bbase, staged);
    k_sortD    <<<NB2, 512, 0, stream>>>(staged, bbase, offsets, ssrc);
    k_transform<<<NTILES, GT, 0, stream>>>(x, W, attS, attD, hb, asrc, adst);
    k_aggregate<<<(N_NODES * 64 + 255) / 256, 256, 0, stream>>>(offsets, ssrc, hb, asrc, adst, gb, gbuf);
    k_finalize <<<NTILES, GT, 0, stream>>>(x, pwt, pb, lng, lnb, gbuf, out);
}

// Round 13
// 107.153 us; speedup vs baseline: 2.7309x; 1.4253x over previous
//
#include <hip/hip_runtime.h>
#include <hip/hip_bf16.h>
#include <math.h>

#define N_NODES 50000
#define N_EDGES 800000
#define DIM 96
#define HEADS 4
#define HEAD_DIM 24
#define SLOPE 0.2f
#define LN_EPS 1e-5f

#define CH 2048                                    // edges per sort chunk
#define NCH ((N_EDGES + CH - 1) / CH)              // 391
#define NB2 ((N_NODES + 255) / 256)                // 196 coarse buckets (dst>>8)

#define NGRP (N_NODES / 16)                        // 3125 (exact)
#define GRID_MM 784                                // 3136 waves >= 3125
#define HLP 100                                    // hl row pad (f32)

typedef __attribute__((ext_vector_type(8))) short bf16x8;
typedef __attribute__((ext_vector_type(4))) float f32x4;

__device__ __forceinline__ unsigned short f2bf(float f) {
    unsigned u = __float_as_uint(f);
    u += 0x7FFFu + ((u >> 16) & 1u);          // round-to-nearest-even
    return (unsigned short)(u >> 16);
}
__device__ __forceinline__ float bf2f(unsigned short v) {
    return __uint_as_float(((unsigned)v) << 16);
}
__device__ __forceinline__ unsigned pack2bf(float a, float b) {
    return (unsigned)f2bf(a) | ((unsigned)f2bf(b) << 16);
}

// ---------------------------------------------------------------------------
// Prep: build bf16 B-fragments for W and PW^T.
// Frag (fb,kc): lane l holds B[k = kc*32 + (l>>4)*8 + j][f = fb*16 + (l&15)],
// j=0..7, stored as 8 bf16 (16B) at ((fb*3+kc)*64 + l)*8.
// Same assumed k-map is used for A-frags in the MM kernels (self-consistent).
// ---------------------------------------------------------------------------
__global__ void k_prep(const float* __restrict__ W, const float* __restrict__ PW,
                       unsigned short* __restrict__ wfr, unsigned short* __restrict__ pwfr)
{
    const int i = blockIdx.x * 256 + threadIdx.x;
    if (i >= 2 * 18 * 64) return;
    const int a = i / (18 * 64);
    const int rem = i % (18 * 64);
    const int frag = rem / 64, lane = rem % 64;
    const int fb = frag / 3, kc = frag % 3;
    const int m = lane & 15, g = lane >> 4;
    unsigned short* dst = (a ? pwfr : wfr) + (size_t)(frag * 64 + lane) * 8;
    #pragma unroll
    for (int j = 0; j < 8; ++j) {
        const int k = kc * 32 + g * 8 + j, f = fb * 16 + m;
        const float v = a ? PW[f * DIM + k] : W[k * DIM + f];   // B[k][f]
        dst[j] = f2bf(v);
    }
}

// ---------------------------------------------------------------------------
// Sort pass A: per-chunk LDS histogram over 196 coarse buckets (no gl atomics)
// ---------------------------------------------------------------------------
__global__ __launch_bounds__(256) void k_sortA(const int* __restrict__ ei,
                                               int* __restrict__ cnt)
{
    __shared__ int h[NB2];
    const int b = blockIdx.x, t = threadIdx.x;
    for (int k = t; k < NB2; k += 256) h[k] = 0;
    __syncthreads();
    const int e0 = b * CH;
    const int e1 = (e0 + CH < N_EDGES) ? e0 + CH : N_EDGES;
    for (int e = e0 + t; e < e1; e += 256) {
        const int d = ei[N_EDGES + e];
        if ((unsigned)d < N_NODES) atomicAdd(&h[d >> 8], 1);
    }
    __syncthreads();
    for (int k = t; k < NB2; k += 256) cnt[k * NCH + b] = h[k];
}

__global__ __launch_bounds__(512) void k_sortB1(const int* __restrict__ cnt,
                                                int* __restrict__ colpre,
                                                int* __restrict__ colsum)
{
    __shared__ int s[512];
    const int k = blockIdx.x, t = threadIdx.x;
    const int v = (t < NCH) ? cnt[k * NCH + t] : 0;
    s[t] = v;
    __syncthreads();
    #pragma unroll
    for (int off = 1; off < 512; off <<= 1) {
        const int u = (t >= off) ? s[t - off] : 0;
        __syncthreads();
        s[t] += u;
        __syncthreads();
    }
    if (t < NCH) colpre[k * NCH + t] = s[t] - v;
    if (t == 511) colsum[k] = s[511];
}

__global__ __launch_bounds__(256) void k_sortB2(const int* __restrict__ colsum,
                                                int* __restrict__ bbase)
{
    __shared__ int s[256];
    const int t = threadIdx.x;
    const int v = (t < NB2) ? colsum[t] : 0;
    s[t] = v;
    __syncthreads();
    #pragma unroll
    for (int off = 1; off < 256; off <<= 1) {
        const int u = (t >= off) ? s[t - off] : 0;
        __syncthreads();
        s[t] += u;
        __syncthreads();
    }
    if (t < NB2) bbase[t] = s[t] - v;
    if (t == 255) bbase[NB2] = s[255];
}

__global__ __launch_bounds__(256) void k_sortC(const int* __restrict__ ei,
                                               const int* __restrict__ colpre,
                                               const int* __restrict__ bbase,
                                               unsigned long long* __restrict__ staged)
{
    __shared__ int lcur[NB2];
    const int b = blockIdx.x, t = threadIdx.x;
    for (int k = t; k < NB2; k += 256) lcur[k] = bbase[k] + colpre[k * NCH + b];
    __syncthreads();
    const int e0 = b * CH;
    const int e1 = (e0 + CH < N_EDGES) ? e0 + CH : N_EDGES;
    for (int e = e0 + t; e < e1; e += 256) {
        int s = ei[e];
        const int d = ei[N_EDGES + e];
        if ((unsigned)d >= N_NODES) continue;
        if ((unsigned)s >= N_NODES) s = d;
        const int pos = atomicAdd(&lcur[d >> 8], 1);
        staged[pos] = (unsigned long long)(unsigned)s |
                      ((unsigned long long)(unsigned)d << 32);
    }
}

__global__ __launch_bounds__(512) void k_sortD(
    const unsigned long long* __restrict__ staged, const int* __restrict__ bbase,
    int* __restrict__ offsets, int* __restrict__ ssrc)
{
    __shared__ int hist[256];
    __shared__ int sc[256];
    const int k = blockIdx.x, t = threadIdx.x;
    const int first = k << 8;
    const int nn = (first + 256 < N_NODES) ? 256 : N_NODES - first;
    const int rs = bbase[k], re = bbase[k + 1];
    if (t < 256) hist[t] = 0;
    __syncthreads();
    for (int i = rs + t; i < re; i += 512) {
        const int d = (int)(staged[i] >> 32);
        atomicAdd(&hist[d - first], 1);
    }
    __syncthreads();
    if (t < 256) sc[t] = hist[t];
    __syncthreads();
    #pragma unroll
    for (int off = 1; off < 256; off <<= 1) {
        int u = 0;
        if (t < 256 && t >= off) u = sc[t - off];
        __syncthreads();
        if (t < 256) sc[t] += u;
        __syncthreads();
    }
    int mycur = 0;
    if (t < 256) {
        mycur = rs + sc[t] - hist[t];
        if (t < nn) offsets[first + t] = mycur;
    }
    if (k == 0 && t == 0) offsets[N_NODES] = bbase[NB2];
    __syncthreads();
    if (t < 256) hist[t] = mycur;
    __syncthreads();
    for (int i = rs + t; i < re; i += 512) {
        const unsigned long long pk = staged[i];
        const int s = (int)(pk & 0xffffffffu);
        const int d = (int)(pk >> 32);
        const int pos = atomicAdd(&hist[d - first], 1);
        ssrc[pos] = s;
    }
}

// ---------------------------------------------------------------------------
// Kernel A (MFMA): h = x @ W. One wave per 16-node group; 18 B-frags in VGPR;
// A-frags built from global x (f32 -> bf16 pack). D layout: col=lane&15 (feat),
// row=(lane>>4)*4+reg (node) [m89]. Att dots via per-wave LDS slice. No barriers.
// ---------------------------------------------------------------------------
__global__ __launch_bounds__(256) void k_transform(
    const float* __restrict__ x, const unsigned short* __restrict__ wfr,
    const float* __restrict__ attS, const float* __restrict__ attD,
    unsigned short* __restrict__ hb, float* __restrict__ asrc,
    float* __restrict__ adst)
{
    __shared__ float hl[4][16][HLP];          // per-wave slices, 25.6 KB
    const int tid = threadIdx.x, wv = tid >> 6, l = tid & 63;
    const int m = l & 15, g = l >> 4;

    bf16x8 wf[6][3];
    #pragma unroll
    for (int fb = 0; fb < 6; ++fb)
        #pragma unroll
        for (int kc = 0; kc < 3; ++kc)
            wf[fb][kc] = *(const bf16x8*)&wfr[(size_t)((fb * 3 + kc) * 64 + l) * 8];

    float (*h)[HLP] = hl[wv];

    for (int grp = blockIdx.x * 4 + wv; grp < NGRP; grp += gridDim.x * 4) {
        const int n0 = grp * 16;
        f32x4 acc[6];
        #pragma unroll
        for (int fb = 0; fb < 6; ++fb)
            #pragma unroll
            for (int e = 0; e < 4; ++e) acc[fb][e] = 0.f;

        #pragma unroll
        for (int kc = 0; kc < 3; ++kc) {
            const float* xp = x + (size_t)(n0 + m) * DIM + kc * 32 + g * 8;
            const float4 xa = *(const float4*)xp;
            const float4 xb = *(const float4*)(xp + 4);
            uint4 au;
            au.x = pack2bf(xa.x, xa.y); au.y = pack2bf(xa.z, xa.w);
            au.z = pack2bf(xb.x, xb.y); au.w = pack2bf(xb.z, xb.w);
            const bf16x8 af = *(const bf16x8*)&au;
            #pragma unroll
            for (int fb = 0; fb < 6; ++fb)
                acc[fb] = __builtin_amdgcn_mfma_f32_16x16x32_bf16(af, wf[fb][kc], acc[fb], 0, 0, 0);
        }
        // D -> LDS (f32): node = g*4+r, feat = fb*16+m
        #pragma unroll
        for (int fb = 0; fb < 6; ++fb)
            #pragma unroll
            for (int r = 0; r < 4; ++r)
                h[g * 4 + r][fb * 16 + m] = acc[fb][r];

        // attention dots: lane -> (node = l>>2, head = l&3)
        {
            const int nd = l >> 2, hd = l & 3;
            const float* hr = &h[nd][hd * HEAD_DIM];
            const float* as_ = attS + hd * HEAD_DIM;
            const float* ad_ = attD + hd * HEAD_DIM;
            float s = 0.f, dd = 0.f;
            #pragma unroll
            for (int kk = 0; kk < HEAD_DIM; ++kk) {
                const float hv = hr[kk];
                s += hv * as_[kk];
                dd += hv * ad_[kk];
            }
            asrc[n0 * HEADS + l] = s;     // (node,head) flat = l
            adst[n0 * HEADS + l] = dd;
        }
        // h -> bf16 global (16 rows x 12 uint4)
        #pragma unroll
        for (int c = l; c < 192; c += 64) {
            const int n = c / 12, q = c % 12;
            const float4 lo = *(const float4*)&h[n][q * 8];
            const float4 hi = *(const float4*)&h[n][q * 8 + 4];
            uint4 hv;
            hv.x = pack2bf(lo.x, lo.y); hv.y = pack2bf(lo.z, lo.w);
            hv.z = pack2bf(hi.x, hi.y); hv.w = pack2bf(hi.z, hi.w);
            *(uint4*)&hb[(size_t)(n0 + n) * DIM + q * 8] = hv;
        }
    }
}

// ---------------------------------------------------------------------------
// Kernel C: gather-aggregate, 8-deep software pipeline (unchanged, R12).
// ---------------------------------------------------------------------------
__global__ __launch_bounds__(256) void k_aggregate(
    const int* __restrict__ offsets, const int* __restrict__ ssrc,
    const unsigned short* __restrict__ hb, const float* __restrict__ asrc,
    const float* __restrict__ adst, const float* __restrict__ gb,
    unsigned short* __restrict__ gbuf)
{
    const int wid  = (blockIdx.x * 256 + threadIdx.x) >> 6;
    const int lane = threadIdx.x & 63;
    if (wid >= N_NODES) return;
    const int d = wid;
    const int lp = (lane < 48) ? lane : 47;
    const int f0 = lp * 2;
    const int hd = f0 / HEAD_DIM;

    const int rs = offsets[d], re = offsets[d + 1];
    const int deg = re - rs;
    const int sv = (lane < deg) ? ssrc[rs + lane] : 0;
    const float adw = adst[d * HEADS + hd];

    float acc0, acc1, ds;
    {
        const unsigned int hp = *(const unsigned int*)&hb[(size_t)d * DIM + f0];
        float l0 = asrc[d * HEADS + hd] + adw;
        l0 = (l0 > 0.f) ? l0 : SLOPE * l0;
        const float w = __expf(l0);
        acc0 = w * bf2f((unsigned short)(hp & 0xffffu));
        acc1 = w * bf2f((unsigned short)(hp >> 16));
        ds = w;
    }

#define SRCJ(j) (((j) < 64) ? __shfl(sv, (j)) : ssrc[rs + (j)])
#define ISSUE(hreg, areg, j) do { \
        const int s_ = SRCJ(j); \
        hreg = *(const unsigned int*)&hb[(size_t)s_ * DIM + f0]; \
        areg = asrc[s_ * HEADS + hd]; } while (0)
#define CONSUME(hreg, areg) do { \
        float l_ = (areg) + adw; l_ = (l_ > 0.f) ? l_ : SLOPE * l_; \
        const float w_ = __expf(l_); \
        acc0 += w_ * bf2f((unsigned short)((hreg) & 0xffffu)); \
        acc1 += w_ * bf2f((unsigned short)((hreg) >> 16)); \
        ds += w_; } while (0)

    int j = 0;
    if (deg >= 8) {
        unsigned p0, p1, p2, p3, p4, p5, p6, p7;
        float    q0, q1, q2, q3, q4, q5, q6, q7;
        ISSUE(p0, q0, 0); ISSUE(p1, q1, 1); ISSUE(p2, q2, 2); ISSUE(p3, q3, 3);
        ISSUE(p4, q4, 4); ISSUE(p5, q5, 5); ISSUE(p6, q6, 6); ISSUE(p7, q7, 7);
        for (; j + 16 <= deg; j += 8) {
            CONSUME(p0, q0); ISSUE(p0, q0, j + 8);
            CONSUME(p1, q1); ISSUE(p1, q1, j + 9);
            CONSUME(p2, q2); ISSUE(p2, q2, j + 10);
            CONSUME(p3, q3); ISSUE(p3, q3, j + 11);
            CONSUME(p4, q4); ISSUE(p4, q4, j + 12);
            CONSUME(p5, q5); ISSUE(p5, q5, j + 13);
            CONSUME(p6, q6); ISSUE(p6, q6, j + 14);
            CONSUME(p7, q7); ISSUE(p7, q7, j + 15);
        }
        CONSUME(p0, q0); CONSUME(p1, q1); CONSUME(p2, q2); CONSUME(p3, q3);
        CONSUME(p4, q4); CONSUME(p5, q5); CONSUME(p6, q6); CONSUME(p7, q7);
        j += 8;
    }
    if (j + 4 <= deg) {
        unsigned pa, pb_, pc, pd;
        float    qa, qb, qc, qd;
        ISSUE(pa, qa, j); ISSUE(pb_, qb, j + 1); ISSUE(pc, qc, j + 2); ISSUE(pd, qd, j + 3);
        CONSUME(pa, qa); CONSUME(pb_, qb); CONSUME(pc, qc); CONSUME(pd, qd);
        j += 4;
    }
    for (; j < deg; ++j) {
        unsigned hh; float aa;
        ISSUE(hh, aa, j); CONSUME(hh, aa);
    }
#undef SRCJ
#undef ISSUE
#undef CONSUME

    if (lane < 48) {
        const float inv = 1.f / ds;
        const float o0 = acc0 * inv + gb[f0];
        const float o1 = acc1 * inv + gb[f0 + 1];
        *(unsigned*)&gbuf[(size_t)d * DIM + f0] = pack2bf(o0, o1);
    }
}

// ---------------------------------------------------------------------------
// Kernel D (MFMA): proj = g @ PW^T + pb, + residual + LayerNorm.
// A-frags are single uint4 loads from gbuf (already bf16). LN fully
// in-register via 16-lane shfl_xor reductions. No LDS, no barriers.
// ---------------------------------------------------------------------------
__global__ __launch_bounds__(256) void k_finalize(
    const float* __restrict__ x, const unsigned short* __restrict__ pwfr,
    const float* __restrict__ pb, const float* __restrict__ lng,
    const float* __restrict__ lnb, const unsigned short* __restrict__ gbuf,
    float* __restrict__ out)
{
    const int tid = threadIdx.x, wv = tid >> 6, l = tid & 63;
    const int m = l & 15, g = l >> 4;

    bf16x8 wf[6][3];
    #pragma unroll
    for (int fb = 0; fb < 6; ++fb)
        #pragma unroll
        for (int kc = 0; kc < 3; ++kc)
            wf[fb][kc] = *(const bf16x8*)&pwfr[(size_t)((fb * 3 + kc) * 64 + l) * 8];

    float pbv[6], lgv[6], lbv[6];
    #pragma unroll
    for (int fb = 0; fb < 6; ++fb) {
        pbv[fb] = pb[fb * 16 + m];
        lgv[fb] = lng[fb * 16 + m];
        lbv[fb] = lnb[fb * 16 + m];
    }

    for (int grp = blockIdx.x * 4 + wv; grp < NGRP; grp += gridDim.x * 4) {
        const int n0 = grp * 16;
        f32x4 acc[6];
        #pragma unroll
        for (int fb = 0; fb < 6; ++fb)
            #pragma unroll
            for (int e = 0; e < 4; ++e) acc[fb][e] = 0.f;

        #pragma unroll
        for (int kc = 0; kc < 3; ++kc) {
            const bf16x8 af = *(const bf16x8*)&gbuf[(size_t)(n0 + m) * DIM + kc * 32 + g * 8];
            #pragma unroll
            for (int fb = 0; fb < 6; ++fb)
                acc[fb] = __builtin_amdgcn_mfma_f32_16x16x32_bf16(af, wf[fb][kc], acc[fb], 0, 0, 0);
        }

        // z = proj + pb + x ; per-node stats across 16 lanes (feat dim)
        float z[6][4];
        float s0 = 0.f, s1 = 0.f, s2 = 0.f, s3 = 0.f;
        float q0 = 0.f, q1 = 0.f, q2 = 0.f, q3 = 0.f;
        #pragma unroll
        for (int fb = 0; fb < 6; ++fb) {
            #pragma unroll
            for (int r = 0; r < 4; ++r) {
                const float zv = acc[fb][r] + pbv[fb] +
                    x[(size_t)(n0 + g * 4 + r) * DIM + fb * 16 + m];
                z[fb][r] = zv;
                if (r == 0) { s0 += zv; q0 += zv * zv; }
                else if (r == 1) { s1 += zv; q1 += zv * zv; }
                else if (r == 2) { s2 += zv; q2 += zv * zv; }
                else { s3 += zv; q3 += zv * zv; }
            }
        }
        #pragma unroll
        for (int mask = 1; mask < 16; mask <<= 1) {
            s0 += __shfl_xor(s0, mask); q0 += __shfl_xor(q0, mask);
            s1 += __shfl_xor(s1, mask); q1 += __shfl_xor(q1, mask);
            s2 += __shfl_xor(s2, mask); q2 += __shfl_xor(q2, mask);
            s3 += __shfl_xor(s3, mask); q3 += __shfl_xor(q3, mask);
        }
        float mu[4], iv[4];
        mu[0] = s0 * (1.f / DIM); iv[0] = rsqrtf(q0 * (1.f / DIM) - mu[0] * mu[0] + LN_EPS);
        mu[1] = s1 * (1.f / DIM); iv[1] = rsqrtf(q1 * (1.f / DIM) - mu[1] * mu[1] + LN_EPS);
        mu[2] = s2 * (1.f / DIM); iv[2] = rsqrtf(q2 * (1.f / DIM) - mu[2] * mu[2] + LN_EPS);
        mu[3] = s3 * (1.f / DIM); iv[3] = rsqrtf(q3 * (1.f / DIM) - mu[3] * mu[3] + LN_EPS);

        #pragma unroll
        for (int fb = 0; fb < 6; ++fb)
            #pragma unroll
            for (int r = 0; r < 4; ++r)
                out[(size_t)(n0 + g * 4 + r) * DIM + fb * 16 + m] =
                    lgv[fb] * (z[fb][r] - mu[r]) * iv[r] + lbv[fb];
    }
}

// ---------------------------------------------------------------------------
extern "C" void kernel_launch(void* const* d_in, const int* in_sizes, int n_in,
                              void* d_out, int out_size, void* d_ws, size_t ws_size,
                              hipStream_t stream)
{
    const float* x    = (const float*)d_in[0];
    const int*   ei   = (const int*)d_in[1];     // [2, E] int32 (harness-converted)
    const float* W    = (const float*)d_in[2];
    const float* attS = (const float*)d_in[3];
    const float* attD = (const float*)d_in[4];
    const float* gb   = (const float*)d_in[5];
    const float* PW   = (const float*)d_in[6];
    const float* pb   = (const float*)d_in[7];
    const float* lng  = (const float*)d_in[8];
    const float* lnb  = (const float*)d_in[9];
    float* out = (float*)d_out;

    char* ws = (char*)d_ws;
    unsigned long long* staged = (unsigned long long*)ws;         // E*8 (6.4 MB)
    float* asrc    = (float*)(staged + N_EDGES);                  // N*4
    float* adst    = asrc + N_NODES * HEADS;                      // N*4
    unsigned short* hb    = (unsigned short*)(adst + N_NODES * HEADS); // N*96 bf16
    unsigned short* gbuf  = hb + (size_t)N_NODES * DIM;           // N*96 bf16
    unsigned short* wfrag = gbuf + (size_t)N_NODES * DIM;         // 18*64*8 bf16
    unsigned short* pwfrag= wfrag + 18 * 64 * 8;                  // 18*64*8 bf16
    int*   cnt     = (int*)(pwfrag + 18 * 64 * 8);                // NB2*NCH
    int*   colpre  = cnt + NB2 * NCH;                             // NB2*NCH
    int*   colsum  = colpre + NB2 * NCH;                          // NB2
    int*   bbase   = colsum + NB2;                                // NB2+1
    int*   offsets = bbase + NB2 + 1;                             // N+1
    int*   ssrc    = offsets + N_NODES + 1;                       // E

    k_prep     <<<9, 256, 0, stream>>>(W, PW, wfrag, pwfrag);
    k_sortA    <<<NCH, 256, 0, stream>>>(ei, cnt);
    k_sortB1   <<<NB2, 512, 0, stream>>>(cnt, colpre, colsum);
    k_sortB2   <<<1, 256, 0, stream>>>(colsum, bbase);
    k_sortC    <<<NCH, 256, 0, stream>>>(ei, colpre, bbase, staged);
    k_sortD    <<<NB2, 512, 0, stream>>>(staged, bbase, offsets, ssrc);
    k_transform<<<GRID_MM, 256, 0, stream>>>(x, wfrag, attS, attD, hb, asrc, adst);
    k_aggregate<<<(N_NODES * 64 + 255) / 256, 256, 0, stream>>>(offsets, ssrc, hb, asrc, adst, gb, gbuf);
    k_finalize <<<GRID_MM, 256, 0, stream>>>(x, pwfrag, pb, lng, lnb, gbuf, out);
}

// Round 14
// 87.489 us; speedup vs baseline: 3.3448x; 1.2248x over previous
//
#include <hip/hip_runtime.h>
#include <hip/hip_bf16.h>
#include <math.h>

#define N_NODES 50000
#define N_EDGES 800000
#define DIM 96
#define HEADS 4
#define HEAD_DIM 24
#define SLOPE 0.2f
#define LN_EPS 1e-5f

#define CH 2048                                    // edges per sort chunk
#define NCH ((N_EDGES + CH - 1) / CH)              // 391
#define NB2 ((N_NODES + 255) / 256)                // 196 coarse buckets (dst>>8)

#define NGRP (N_NODES / 16)                        // 3125 (exact)
#define GRID_MM 784                                // 3136 waves >= 3125
#define HLP 100                                    // hl row pad (f32)

typedef __attribute__((ext_vector_type(8))) short bf16x8;
typedef __attribute__((ext_vector_type(4))) float f32x4;

__device__ __forceinline__ unsigned short f2bf(float f) {
    unsigned u = __float_as_uint(f);
    u += 0x7FFFu + ((u >> 16) & 1u);          // round-to-nearest-even
    return (unsigned short)(u >> 16);
}
__device__ __forceinline__ float bf2f(unsigned short v) {
    return __uint_as_float(((unsigned)v) << 16);
}
__device__ __forceinline__ unsigned pack2bf(float a, float b) {
    return (unsigned)f2bf(a) | ((unsigned)f2bf(b) << 16);
}

// ---------------------------------------------------------------------------
// Sort pass A (+fused prep): blocks 0-8 also build the bf16 B-fragments for
// W and PW^T (consumed much later by transform/finalize). Then per-chunk LDS
// histogram over 196 coarse buckets. No global atomics.
// ---------------------------------------------------------------------------
__global__ __launch_bounds__(256) void k_sortA(
    const int* __restrict__ ei, int* __restrict__ cnt,
    const float* __restrict__ W, const float* __restrict__ PW,
    unsigned short* __restrict__ wfr, unsigned short* __restrict__ pwfr)
{
    const int gi = blockIdx.x * 256 + threadIdx.x;
    if (gi < 2 * 18 * 64) {                       // fused k_prep
        const int a = gi / (18 * 64);
        const int rem = gi % (18 * 64);
        const int frag = rem / 64, lane = rem % 64;
        const int fb = frag / 3, kc = frag % 3;
        const int m = lane & 15, g = lane >> 4;
        unsigned short* dst = (a ? pwfr : wfr) + (size_t)(frag * 64 + lane) * 8;
        #pragma unroll
        for (int j = 0; j < 8; ++j) {
            const int k = kc * 32 + g * 8 + j, f = fb * 16 + m;
            const float v = a ? PW[f * DIM + k] : W[k * DIM + f];   // B[k][f]
            dst[j] = f2bf(v);
        }
    }
    __shared__ int h[NB2];
    const int b = blockIdx.x, t = threadIdx.x;
    for (int k = t; k < NB2; k += 256) h[k] = 0;
    __syncthreads();
    const int e0 = b * CH;
    const int e1 = (e0 + CH < N_EDGES) ? e0 + CH : N_EDGES;
    for (int e = e0 + t; e < e1; e += 256) {
        const int d = ei[N_EDGES + e];
        if ((unsigned)d < N_NODES) atomicAdd(&h[d >> 8], 1);
    }
    __syncthreads();
    for (int k = t; k < NB2; k += 256) cnt[k * NCH + b] = h[k];
}

__global__ __launch_bounds__(512) void k_sortB1(const int* __restrict__ cnt,
                                                int* __restrict__ colpre,
                                                int* __restrict__ colsum)
{
    __shared__ int s[512];
    const int k = blockIdx.x, t = threadIdx.x;
    const int v = (t < NCH) ? cnt[k * NCH + t] : 0;
    s[t] = v;
    __syncthreads();
    #pragma unroll
    for (int off = 1; off < 512; off <<= 1) {
        const int u = (t >= off) ? s[t - off] : 0;
        __syncthreads();
        s[t] += u;
        __syncthreads();
    }
    if (t < NCH) colpre[k * NCH + t] = s[t] - v;
    if (t == 511) colsum[k] = s[511];
}

__global__ __launch_bounds__(256) void k_sortB2(const int* __restrict__ colsum,
                                                int* __restrict__ bbase)
{
    __shared__ int s[256];
    const int t = threadIdx.x;
    const int v = (t < NB2) ? colsum[t] : 0;
    s[t] = v;
    __syncthreads();
    #pragma unroll
    for (int off = 1; off < 256; off <<= 1) {
        const int u = (t >= off) ? s[t - off] : 0;
        __syncthreads();
        s[t] += u;
        __syncthreads();
    }
    if (t < NB2) bbase[t] = s[t] - v;
    if (t == 255) bbase[NB2] = s[255];
}

// ---------------------------------------------------------------------------
// Sort pass C: place packed (s | d_local<<16) into coarse-bucket order.
// 4B per edge (s < 2^16, d_local < 2^8). LDS cursors only.
// ---------------------------------------------------------------------------
__global__ __launch_bounds__(256) void k_sortC(const int* __restrict__ ei,
                                               const int* __restrict__ colpre,
                                               const int* __restrict__ bbase,
                                               unsigned* __restrict__ staged)
{
    __shared__ int lcur[NB2];
    const int b = blockIdx.x, t = threadIdx.x;
    for (int k = t; k < NB2; k += 256) lcur[k] = bbase[k] + colpre[k * NCH + b];
    __syncthreads();
    const int e0 = b * CH;
    const int e1 = (e0 + CH < N_EDGES) ? e0 + CH : N_EDGES;
    for (int e = e0 + t; e < e1; e += 256) {
        int s = ei[e];
        const int d = ei[N_EDGES + e];
        if ((unsigned)d >= N_NODES) continue;
        if ((unsigned)s >= N_NODES) s = d;
        const int pos = atomicAdd(&lcur[d >> 8], 1);
        staged[pos] = (unsigned)s | ((unsigned)(d & 255) << 16);
    }
}

__global__ __launch_bounds__(512) void k_sortD(
    const unsigned* __restrict__ staged, const int* __restrict__ bbase,
    int* __restrict__ offsets, int* __restrict__ ssrc)
{
    __shared__ int hist[256];
    __shared__ int sc[256];
    const int k = blockIdx.x, t = threadIdx.x;
    const int first = k << 8;
    const int nn = (first + 256 < N_NODES) ? 256 : N_NODES - first;
    const int rs = bbase[k], re = bbase[k + 1];
    if (t < 256) hist[t] = 0;
    __syncthreads();
    for (int i = rs + t; i < re; i += 512)
        atomicAdd(&hist[staged[i] >> 16], 1);
    __syncthreads();
    if (t < 256) sc[t] = hist[t];
    __syncthreads();
    #pragma unroll
    for (int off = 1; off < 256; off <<= 1) {
        int u = 0;
        if (t < 256 && t >= off) u = sc[t - off];
        __syncthreads();
        if (t < 256) sc[t] += u;
        __syncthreads();
    }
    int mycur = 0;
    if (t < 256) {
        mycur = rs + sc[t] - hist[t];
        if (t < nn) offsets[first + t] = mycur;
    }
    if (k == 0 && t == 0) offsets[N_NODES] = bbase[NB2];
    __syncthreads();
    if (t < 256) hist[t] = mycur;
    __syncthreads();
    for (int i = rs + t; i < re; i += 512) {
        const unsigned pk = staged[i];
        const int pos = atomicAdd(&hist[pk >> 16], 1);
        ssrc[pos] = (int)(pk & 0xffffu);
    }
}

// ---------------------------------------------------------------------------
// Kernel A (MFMA): h = x @ W. One wave per 16-node group; 18 B-frags in VGPR.
// ---------------------------------------------------------------------------
__global__ __launch_bounds__(256) void k_transform(
    const float* __restrict__ x, const unsigned short* __restrict__ wfr,
    const float* __restrict__ attS, const float* __restrict__ attD,
    unsigned short* __restrict__ hb, float* __restrict__ asrc,
    float* __restrict__ adst)
{
    __shared__ float hl[4][16][HLP];          // per-wave slices, 25.6 KB
    const int tid = threadIdx.x, wv = tid >> 6, l = tid & 63;
    const int m = l & 15, g = l >> 4;

    bf16x8 wf[6][3];
    #pragma unroll
    for (int fb = 0; fb < 6; ++fb)
        #pragma unroll
        for (int kc = 0; kc < 3; ++kc)
            wf[fb][kc] = *(const bf16x8*)&wfr[(size_t)((fb * 3 + kc) * 64 + l) * 8];

    float (*h)[HLP] = hl[wv];

    for (int grp = blockIdx.x * 4 + wv; grp < NGRP; grp += gridDim.x * 4) {
        const int n0 = grp * 16;
        f32x4 acc[6];
        #pragma unroll
        for (int fb = 0; fb < 6; ++fb)
            #pragma unroll
            for (int e = 0; e < 4; ++e) acc[fb][e] = 0.f;

        #pragma unroll
        for (int kc = 0; kc < 3; ++kc) {
            const float* xp = x + (size_t)(n0 + m) * DIM + kc * 32 + g * 8;
            const float4 xa = *(const float4*)xp;
            const float4 xb = *(const float4*)(xp + 4);
            uint4 au;
            au.x = pack2bf(xa.x, xa.y); au.y = pack2bf(xa.z, xa.w);
            au.z = pack2bf(xb.x, xb.y); au.w = pack2bf(xb.z, xb.w);
            const bf16x8 af = *(const bf16x8*)&au;
            #pragma unroll
            for (int fb = 0; fb < 6; ++fb)
                acc[fb] = __builtin_amdgcn_mfma_f32_16x16x32_bf16(af, wf[fb][kc], acc[fb], 0, 0, 0);
        }
        #pragma unroll
        for (int fb = 0; fb < 6; ++fb)
            #pragma unroll
            for (int r = 0; r < 4; ++r)
                h[g * 4 + r][fb * 16 + m] = acc[fb][r];

        {   // attention dots: lane -> (node = l>>2, head = l&3)
            const int nd = l >> 2, hd = l & 3;
            const float* hr = &h[nd][hd * HEAD_DIM];
            const float* as_ = attS + hd * HEAD_DIM;
            const float* ad_ = attD + hd * HEAD_DIM;
            float s = 0.f, dd = 0.f;
            #pragma unroll
            for (int kk = 0; kk < HEAD_DIM; ++kk) {
                const float hv = hr[kk];
                s += hv * as_[kk];
                dd += hv * ad_[kk];
            }
            asrc[n0 * HEADS + l] = s;
            adst[n0 * HEADS + l] = dd;
        }
        #pragma unroll
        for (int c = l; c < 192; c += 64) {
            const int n = c / 12, q = c % 12;
            const float4 lo = *(const float4*)&h[n][q * 8];
            const float4 hi = *(const float4*)&h[n][q * 8 + 4];
            uint4 hv;
            hv.x = pack2bf(lo.x, lo.y); hv.y = pack2bf(lo.z, lo.w);
            hv.z = pack2bf(hi.x, hi.y); hv.w = pack2bf(hi.z, hi.w);
            *(uint4*)&hb[(size_t)(n0 + n) * DIM + q * 8] = hv;
        }
    }
}

// ---------------------------------------------------------------------------
// Kernel C: gather-aggregate. Batch weight phase: lane j computes edge j's
// 4 head-weights (one float4 asrc gather + 4 exps per <=64 edges), parks in
// per-wave LDS; h-loop reads w via conflict-free ds_read. 8-deep h pipeline.
// ---------------------------------------------------------------------------
__global__ __launch_bounds__(256) void k_aggregate(
    const int* __restrict__ offsets, const int* __restrict__ ssrc,
    const unsigned short* __restrict__ hb, const float* __restrict__ asrc,
    const float* __restrict__ adst, const float* __restrict__ gb,
    unsigned short* __restrict__ gbuf)
{
    __shared__ float wlds[4][256];               // per-wave 64 edges x 4 heads
    const int wid  = (blockIdx.x * 256 + threadIdx.x) >> 6;
    const int lane = threadIdx.x & 63;
    if (wid >= N_NODES) return;
    const int wv = (threadIdx.x >> 6) & 3;
    const int d = wid;
    const int lp = (lane < 48) ? lane : 47;      // lanes 48-63 duplicate lane 47
    const int f0 = lp * 2;                       // features f0, f0+1 (same head)
    const int hd = f0 / HEAD_DIM;

    const int rs = offsets[d], re = offsets[d + 1];
    const int deg = re - rs;
    const int sv = (lane < deg) ? ssrc[rs + lane] : d;   // coalesced preload

    {   // batch weights: lane j -> edge j (valid dummy for j >= deg)
        const float4 as = *(const float4*)&asrc[sv * 4];
        const float4 ad = *(const float4*)&adst[d * 4];
        float l; float4 w;
        l = as.x + ad.x; l = (l > 0.f) ? l : SLOPE * l; w.x = __expf(l);
        l = as.y + ad.y; l = (l > 0.f) ? l : SLOPE * l; w.y = __expf(l);
        l = as.z + ad.z; l = (l > 0.f) ? l : SLOPE * l; w.z = __expf(l);
        l = as.w + ad.w; l = (l > 0.f) ? l : SLOPE * l; w.w = __expf(l);
        *(float4*)&wlds[wv][lane * 4] = w;       // wave-synchronous, no barrier
    }

    float acc0, acc1, ds;
    {   // self-loop term
        const unsigned hp = *(const unsigned*)&hb[(size_t)d * DIM + f0];
        float l0 = asrc[d * HEADS + hd] + adst[d * HEADS + hd];
        l0 = (l0 > 0.f) ? l0 : SLOPE * l0;
        const float w = __expf(l0);
        acc0 = w * bf2f((unsigned short)(hp & 0xffffu));
        acc1 = w * bf2f((unsigned short)(hp >> 16));
        ds = w;
    }

#define ISSUE(hreg, wreg, j) do { \
        const int s_ = __shfl(sv, (j)); \
        hreg = *(const unsigned*)&hb[(size_t)s_ * DIM + f0]; \
        wreg = wlds[wv][(j) * 4 + hd]; } while (0)
#define CONSUME(hreg, wreg) do { \
        acc0 += (wreg) * bf2f((unsigned short)((hreg) & 0xffffu)); \
        acc1 += (wreg) * bf2f((unsigned short)((hreg) >> 16)); \
        ds += (wreg); } while (0)

    const int nd = (deg < 64) ? deg : 64;
    int j = 0;
    if (nd >= 8) {                               // 8-deep main pipeline
        unsigned p0, p1, p2, p3, p4, p5, p6, p7;
        float    q0, q1, q2, q3, q4, q5, q6, q7;
        ISSUE(p0, q0, 0); ISSUE(p1, q1, 1); ISSUE(p2, q2, 2); ISSUE(p3, q3, 3);
        ISSUE(p4, q4, 4); ISSUE(p5, q5, 5); ISSUE(p6, q6, 6); ISSUE(p7, q7, 7);
        for (; j + 16 <= nd; j += 8) {
            CONSUME(p0, q0); ISSUE(p0, q0, j + 8);
            CONSUME(p1, q1); ISSUE(p1, q1, j + 9);
            CONSUME(p2, q2); ISSUE(p2, q2, j + 10);
            CONSUME(p3, q3); ISSUE(p3, q3, j + 11);
            CONSUME(p4, q4); ISSUE(p4, q4, j + 12);
            CONSUME(p5, q5); ISSUE(p5, q5, j + 13);
            CONSUME(p6, q6); ISSUE(p6, q6, j + 14);
            CONSUME(p7, q7); ISSUE(p7, q7, j + 15);
        }
        CONSUME(p0, q0); CONSUME(p1, q1); CONSUME(p2, q2); CONSUME(p3, q3);
        CONSUME(p4, q4); CONSUME(p5, q5); CONSUME(p6, q6); CONSUME(p7, q7);
        j += 8;
    }
    if (j + 4 <= nd) {                           // 4-deep drain
        unsigned pa, pb_, pc, pd;
        float    qa, qb, qc, qd;
        ISSUE(pa, qa, j); ISSUE(pb_, qb, j + 1); ISSUE(pc, qc, j + 2); ISSUE(pd, qd, j + 3);
        CONSUME(pa, qa); CONSUME(pb_, qb); CONSUME(pc, qc); CONSUME(pd, qd);
        j += 4;
    }
    for (; j < nd; ++j) {                        // <=3 scalar tail
        unsigned hh; float ww;
        ISSUE(hh, ww, j); CONSUME(hh, ww);
    }
#undef ISSUE
#undef CONSUME
    for (j = 64; j < deg; ++j) {                 // rare deg>64: inline weights
        const int s_ = ssrc[rs + j];
        const unsigned hh = *(const unsigned*)&hb[(size_t)s_ * DIM + f0];
        float l_ = asrc[s_ * HEADS + hd] + adst[d * HEADS + hd];
        l_ = (l_ > 0.f) ? l_ : SLOPE * l_;
        const float w_ = __expf(l_);
        acc0 += w_ * bf2f((unsigned short)(hh & 0xffffu));
        acc1 += w_ * bf2f((unsigned short)(hh >> 16));
        ds += w_;
    }

    if (lane < 48) {
        const float inv = 1.f / ds;              // ds > 0 (self-loop)
        const float o0 = acc0 * inv + gb[f0];
        const float o1 = acc1 * inv + gb[f0 + 1];
        *(unsigned*)&gbuf[(size_t)d * DIM + f0] = pack2bf(o0, o1);
    }
}

// ---------------------------------------------------------------------------
// Kernel D (MFMA): proj = g @ PW^T + pb, + residual + LayerNorm, in-register.
// ---------------------------------------------------------------------------
__global__ __launch_bounds__(256) void k_finalize(
    const float* __restrict__ x, const unsigned short* __restrict__ pwfr,
    const float* __restrict__ pb, const float* __restrict__ lng,
    const float* __restrict__ lnb, const unsigned short* __restrict__ gbuf,
    float* __restrict__ out)
{
    const int tid = threadIdx.x, wv = tid >> 6, l = tid & 63;
    const int m = l & 15, g = l >> 4;

    bf16x8 wf[6][3];
    #pragma unroll
    for (int fb = 0; fb < 6; ++fb)
        #pragma unroll
        for (int kc = 0; kc < 3; ++kc)
            wf[fb][kc] = *(const bf16x8*)&pwfr[(size_t)((fb * 3 + kc) * 64 + l) * 8];

    float pbv[6], lgv[6], lbv[6];
    #pragma unroll
    for (int fb = 0; fb < 6; ++fb) {
        pbv[fb] = pb[fb * 16 + m];
        lgv[fb] = lng[fb * 16 + m];
        lbv[fb] = lnb[fb * 16 + m];
    }

    for (int grp = blockIdx.x * 4 + wv; grp < NGRP; grp += gridDim.x * 4) {
        const int n0 = grp * 16;
        f32x4 acc[6];
        #pragma unroll
        for (int fb = 0; fb < 6; ++fb)
            #pragma unroll
            for (int e = 0; e < 4; ++e) acc[fb][e] = 0.f;

        #pragma unroll
        for (int kc = 0; kc < 3; ++kc) {
            const bf16x8 af = *(const bf16x8*)&gbuf[(size_t)(n0 + m) * DIM + kc * 32 + g * 8];
            #pragma unroll
            for (int fb = 0; fb < 6; ++fb)
                acc[fb] = __builtin_amdgcn_mfma_f32_16x16x32_bf16(af, wf[fb][kc], acc[fb], 0, 0, 0);
        }

        float z[6][4];
        float s0 = 0.f, s1 = 0.f, s2 = 0.f, s3 = 0.f;
        float q0 = 0.f, q1 = 0.f, q2 = 0.f, q3 = 0.f;
        #pragma unroll
        for (int fb = 0; fb < 6; ++fb) {
            #pragma unroll
            for (int r = 0; r < 4; ++r) {
                const float zv = acc[fb][r] + pbv[fb] +
                    x[(size_t)(n0 + g * 4 + r) * DIM + fb * 16 + m];
                z[fb][r] = zv;
                if (r == 0) { s0 += zv; q0 += zv * zv; }
                else if (r == 1) { s1 += zv; q1 += zv * zv; }
                else if (r == 2) { s2 += zv; q2 += zv * zv; }
                else { s3 += zv; q3 += zv * zv; }
            }
        }
        #pragma unroll
        for (int mask = 1; mask < 16; mask <<= 1) {
            s0 += __shfl_xor(s0, mask); q0 += __shfl_xor(q0, mask);
            s1 += __shfl_xor(s1, mask); q1 += __shfl_xor(q1, mask);
            s2 += __shfl_xor(s2, mask); q2 += __shfl_xor(q2, mask);
            s3 += __shfl_xor(s3, mask); q3 += __shfl_xor(q3, mask);
        }
        float mu[4], iv[4];
        mu[0] = s0 * (1.f / DIM); iv[0] = rsqrtf(q0 * (1.f / DIM) - mu[0] * mu[0] + LN_EPS);
        mu[1] = s1 * (1.f / DIM); iv[1] = rsqrtf(q1 * (1.f / DIM) - mu[1] * mu[1] + LN_EPS);
        mu[2] = s2 * (1.f / DIM); iv[2] = rsqrtf(q2 * (1.f / DIM) - mu[2] * mu[2] + LN_EPS);
        mu[3] = s3 * (1.f / DIM); iv[3] = rsqrtf(q3 * (1.f / DIM) - mu[3] * mu[3] + LN_EPS);

        #pragma unroll
        for (int fb = 0; fb < 6; ++fb)
            #pragma unroll
            for (int r = 0; r < 4; ++r)
                out[(size_t)(n0 + g * 4 + r) * DIM + fb * 16 + m] =
                    lgv[fb] * (z[fb][r] - mu[r]) * iv[r] + lbv[fb];
    }
}

// ---------------------------------------------------------------------------
extern "C" void kernel_launch(void* const* d_in, const int* in_sizes, int n_in,
                              void* d_out, int out_size, void* d_ws, size_t ws_size,
                              hipStream_t stream)
{
    const float* x    = (const float*)d_in[0];
    const int*   ei   = (const int*)d_in[1];     // [2, E] int32 (harness-converted)
    const float* W    = (const float*)d_in[2];
    const float* attS = (const float*)d_in[3];
    const float* attD = (const float*)d_in[4];
    const float* gb   = (const float*)d_in[5];
    const float* PW   = (const float*)d_in[6];
    const float* pb   = (const float*)d_in[7];
    const float* lng  = (const float*)d_in[8];
    const float* lnb  = (const float*)d_in[9];
    float* out = (float*)d_out;

    char* ws = (char*)d_ws;
    unsigned* staged = (unsigned*)ws;                             // E*4 (3.2 MB)
    float* asrc    = (float*)(staged + N_EDGES);                  // N*4
    float* adst    = asrc + N_NODES * HEADS;                      // N*4
    unsigned short* hb    = (unsigned short*)(adst + N_NODES * HEADS); // N*96 bf16
    unsigned short* gbuf  = hb + (size_t)N_NODES * DIM;           // N*96 bf16
    unsigned short* wfrag = gbuf + (size_t)N_NODES * DIM;         // 18*64*8 bf16
    unsigned short* pwfrag= wfrag + 18 * 64 * 8;                  // 18*64*8 bf16
    int*   cnt     = (int*)(pwfrag + 18 * 64 * 8);                // NB2*NCH
    int*   colpre  = cnt + NB2 * NCH;                             // NB2*NCH
    int*   colsum  = colpre + NB2 * NCH;                          // NB2
    int*   bbase   = colsum + NB2;                                // NB2+1
    int*   offsets = bbase + NB2 + 1;                             // N+1
    int*   ssrc    = offsets + N_NODES + 1;                       // E

    k_sortA    <<<NCH, 256, 0, stream>>>(ei, cnt, W, PW, wfrag, pwfrag);
    k_sortB1   <<<NB2, 512, 0, stream>>>(cnt, colpre, colsum);
    k_sortB2   <<<1, 256, 0, stream>>>(colsum, bbase);
    k_sortC    <<<NCH, 256, 0, stream>>>(ei, colpre, bbase, staged);
    k_sortD    <<<NB2, 512, 0, stream>>>(staged, bbase, offsets, ssrc);
    k_transform<<<GRID_MM, 256, 0, stream>>>(x, wfrag, attS, attD, hb, asrc, adst);
    k_aggregate<<<(N_NODES * 64 + 255) / 256, 256, 0, stream>>>(offsets, ssrc, hb, asrc, adst, gb, gbuf);
    k_finalize <<<GRID_MM, 256, 0, stream>>>(x, pwfrag, pb, lng, lnb, gbuf, out);
}